// Round 1
// baseline (2943.934 us; speedup 1.0000x reference)
//
#include <hip/hip_runtime.h>
#include <hip/hip_bf16.h>

#define NEG_SLOPE 0.2f

// ---------------------------------------------------------------------------
// GEMM: h[N,128] = x[N,128] @ W[128,128], fp32.
// Block: 256 threads, 64 rows x 128 cols. Thread computes 8 rows x 4 cols.
// ---------------------------------------------------------------------------
__global__ __launch_bounds__(256) void gemm_h(const float* __restrict__ x,
                                              const float* __restrict__ Wm,
                                              float* __restrict__ hout, int N) {
    __shared__ float As[32][68];      // [k][row], padded for store conflicts / 16B align
    __shared__ float Bs[32 * 128];    // [k][col] flat

    const int tid  = threadIdx.x;
    const int row0 = blockIdx.x * 64;
    const int tr   = tid >> 5;        // 0..7  -> rows tr*8 .. tr*8+7
    const int tc   = tid & 31;        // 0..31 -> cols tc*4 .. tc*4+3
    const int r0   = tr * 8;

    float acc[8][4];
#pragma unroll
    for (int i = 0; i < 8; ++i)
#pragma unroll
        for (int j = 0; j < 4; ++j) acc[i][j] = 0.f;

    for (int kc = 0; kc < 4; ++kc) {
        const int k0 = kc * 32;
        // Load A tile (64 rows x 32 ks), transposed into As[k][row]
#pragma unroll
        for (int p = 0; p < 2; ++p) {
            int lr = (tid >> 3) + p * 32;       // 0..63
            int lk = (tid & 7) * 4;             // 0,4,..,28
            int gr = row0 + lr;
            int grc = gr < N ? gr : N - 1;      // clamp; OOB rows never stored
            float4 v = *(const float4*)(x + (size_t)grc * 128 + k0 + lk);
            As[lk + 0][lr] = v.x;
            As[lk + 1][lr] = v.y;
            As[lk + 2][lr] = v.z;
            As[lk + 3][lr] = v.w;
        }
        // Load B tile (32 rows of W x 128 cols) — contiguous chunk
#pragma unroll
        for (int p = 0; p < 4; ++p) {
            int idx = p * 1024 + tid * 4;
            *(float4*)&Bs[idx] = *(const float4*)(Wm + k0 * 128 + idx);
        }
        __syncthreads();
#pragma unroll
        for (int k = 0; k < 32; ++k) {
            float4 a0 = *(const float4*)&As[k][r0];
            float4 a1 = *(const float4*)&As[k][r0 + 4];
            float4 b  = *(const float4*)&Bs[k * 128 + tc * 4];
            float av[8] = {a0.x, a0.y, a0.z, a0.w, a1.x, a1.y, a1.z, a1.w};
            float bv[4] = {b.x, b.y, b.z, b.w};
#pragma unroll
            for (int i = 0; i < 8; ++i)
#pragma unroll
                for (int j = 0; j < 4; ++j) acc[i][j] += av[i] * bv[j];
        }
        __syncthreads();
    }
    // Store
#pragma unroll
    for (int i = 0; i < 8; ++i) {
        int gr = row0 + r0 + i;
        if (gr < N) {
            float4 v = make_float4(acc[i][0], acc[i][1], acc[i][2], acc[i][3]);
            *(float4*)(hout + (size_t)gr * 128 + tc * 4) = v;
        }
    }
}

// ---------------------------------------------------------------------------
// alpha_src / alpha_dst: per (node, head) dot of h[n,h,:] with a_src/a_dst.
// One thread per (node, head).
// ---------------------------------------------------------------------------
__global__ __launch_bounds__(256) void calc_alpha(const float* __restrict__ h,
                                                  const float* __restrict__ a_src,
                                                  const float* __restrict__ a_dst,
                                                  float* __restrict__ as,
                                                  float* __restrict__ ad, int N) {
    int gid = blockIdx.x * 256 + threadIdx.x;
    int n = gid >> 3;
    int hh = gid & 7;
    if (n >= N) return;
    const float4* hp  = (const float4*)(h + (size_t)n * 128 + hh * 16);
    const float4* asp = (const float4*)(a_src + hh * 16);
    const float4* adp = (const float4*)(a_dst + hh * 16);
    float s = 0.f, d = 0.f;
#pragma unroll
    for (int i = 0; i < 4; ++i) {
        float4 hv = hp[i], av = asp[i], bv = adp[i];
        s += hv.x * av.x + hv.y * av.y + hv.z * av.z + hv.w * av.w;
        d += hv.x * bv.x + hv.y * bv.y + hv.z * bv.z + hv.w * bv.w;
    }
    as[gid] = s;
    ad[gid] = d;
}

// ---------------------------------------------------------------------------
// Edge scatter: 32 lanes per edge, each lane handles 4 channels (1 head / 4 lanes).
// w = exp(leaky_relu(as[src]+ad[dst])); atomically add w*h[src] into S, w into D.
// ---------------------------------------------------------------------------
__global__ __launch_bounds__(256) void edge_scatter(const int* __restrict__ ei,
                                                    const float* __restrict__ h,
                                                    const float* __restrict__ as,
                                                    const float* __restrict__ ad,
                                                    float* __restrict__ S,
                                                    float* __restrict__ D, int E) {
    long long gid = (long long)blockIdx.x * 256 + threadIdx.x;
    int e = (int)(gid >> 5);
    int lane = (int)(gid & 31);
    if (e >= E) return;
    int j = ei[e];          // src
    int i = ei[E + e];      // dst
    int hh = lane >> 2;     // head for channels lane*4..lane*4+3
    float t = as[j * 8 + hh] + ad[i * 8 + hh];
    t = t > 0.f ? t : NEG_SLOPE * t;
    float w = __expf(t);
    float4 hv = *(const float4*)(h + (size_t)j * 128 + lane * 4);
    float* Sp = S + (size_t)i * 128 + lane * 4;
    atomicAdd(Sp + 0, w * hv.x);
    atomicAdd(Sp + 1, w * hv.y);
    atomicAdd(Sp + 2, w * hv.z);
    atomicAdd(Sp + 3, w * hv.w);
    if ((lane & 3) == 0) atomicAdd(D + (size_t)i * 8 + hh, w);
}

// ---------------------------------------------------------------------------
// Finalize: fold in self-loop, divide by denom, add bias, ReLU. 32 lanes/node.
// ---------------------------------------------------------------------------
__global__ __launch_bounds__(256) void finalize(const float* __restrict__ h,
                                                const float* __restrict__ as,
                                                const float* __restrict__ ad,
                                                const float* __restrict__ D,
                                                const float* __restrict__ bias,
                                                float* __restrict__ out, int N) {
    long long gid = (long long)blockIdx.x * 256 + threadIdx.x;
    int n = (int)(gid >> 5);
    int lane = (int)(gid & 31);
    if (n >= N) return;
    int hh = lane >> 2;
    float t = as[n * 8 + hh] + ad[n * 8 + hh];
    t = t > 0.f ? t : NEG_SLOPE * t;
    float w = __expf(t);                   // self-loop weight
    float d = D[n * 8 + hh] + w;
    float inv = 1.0f / (d + 1e-16f);
    float4 hv = *(const float4*)(h + (size_t)n * 128 + lane * 4);
    float4 sv = *(const float4*)(out + (size_t)n * 128 + lane * 4);
    float4 bv = *(const float4*)(bias + lane * 4);
    float4 o;
    o.x = (sv.x + w * hv.x) * inv + bv.x;
    o.y = (sv.y + w * hv.y) * inv + bv.y;
    o.z = (sv.z + w * hv.z) * inv + bv.z;
    o.w = (sv.w + w * hv.w) * inv + bv.w;
    o.x = o.x > 0.f ? o.x : 0.f;
    o.y = o.y > 0.f ? o.y : 0.f;
    o.z = o.z > 0.f ? o.z : 0.f;
    o.w = o.w > 0.f ? o.w : 0.f;
    *(float4*)(out + (size_t)n * 128 + lane * 4) = o;
}

extern "C" void kernel_launch(void* const* d_in, const int* in_sizes, int n_in,
                              void* d_out, int out_size, void* d_ws, size_t ws_size,
                              hipStream_t stream) {
    const float* x     = (const float*)d_in[0];
    const int*   ei    = (const int*)d_in[1];
    const float* W     = (const float*)d_in[2];
    const float* a_src = (const float*)d_in[3];
    const float* a_dst = (const float*)d_in[4];
    const float* bias  = (const float*)d_in[5];
    float* out = (float*)d_out;

    const int N = in_sizes[0] / 128;   // 100000
    const int E = in_sizes[1] / 2;     // 1600000

    char* ws = (char*)d_ws;
    float* h  = (float*)ws;                                  // N*128
    float* as = (float*)(ws + (size_t)N * 128 * 4);          // N*8
    float* ad = as + (size_t)N * 8;                          // N*8
    float* D  = ad + (size_t)N * 8;                          // N*8

    hipMemsetAsync(out, 0, (size_t)N * 128 * 4, stream);
    hipMemsetAsync(D, 0, (size_t)N * 8 * 4, stream);

    gemm_h<<<(N + 63) / 64, 256, 0, stream>>>(x, W, h, N);
    calc_alpha<<<(N * 8 + 255) / 256, 256, 0, stream>>>(h, a_src, a_dst, as, ad, N);
    edge_scatter<<<(int)(((long long)E * 32 + 255) / 256), 256, 0, stream>>>(ei, h, as, ad, out, D, E);
    finalize<<<(int)(((long long)N * 32 + 255) / 256), 256, 0, stream>>>(h, as, ad, D, bias, out, N);
}

// Round 2
// 484.815 us; speedup vs baseline: 6.0723x; 6.0723x over previous
//
#include <hip/hip_runtime.h>
#include <hip/hip_bf16.h>

#define NEG_SLOPE 0.2f

// ---------------------------------------------------------------------------
// GEMM: h[N,128] = x[N,128] @ W[128,128], fp32.
// ---------------------------------------------------------------------------
__global__ __launch_bounds__(256) void gemm_h(const float* __restrict__ x,
                                              const float* __restrict__ Wm,
                                              float* __restrict__ hout, int N) {
    __shared__ float As[32][68];
    __shared__ float Bs[32 * 128];

    const int tid  = threadIdx.x;
    const int row0 = blockIdx.x * 64;
    const int tr   = tid >> 5;
    const int tc   = tid & 31;
    const int r0   = tr * 8;

    float acc[8][4];
#pragma unroll
    for (int i = 0; i < 8; ++i)
#pragma unroll
        for (int j = 0; j < 4; ++j) acc[i][j] = 0.f;

    for (int kc = 0; kc < 4; ++kc) {
        const int k0 = kc * 32;
#pragma unroll
        for (int p = 0; p < 2; ++p) {
            int lr = (tid >> 3) + p * 32;
            int lk = (tid & 7) * 4;
            int gr = row0 + lr;
            int grc = gr < N ? gr : N - 1;
            float4 v = *(const float4*)(x + (size_t)grc * 128 + k0 + lk);
            As[lk + 0][lr] = v.x;
            As[lk + 1][lr] = v.y;
            As[lk + 2][lr] = v.z;
            As[lk + 3][lr] = v.w;
        }
#pragma unroll
        for (int p = 0; p < 4; ++p) {
            int idx = p * 1024 + tid * 4;
            *(float4*)&Bs[idx] = *(const float4*)(Wm + k0 * 128 + idx);
        }
        __syncthreads();
#pragma unroll
        for (int k = 0; k < 32; ++k) {
            float4 a0 = *(const float4*)&As[k][r0];
            float4 a1 = *(const float4*)&As[k][r0 + 4];
            float4 b  = *(const float4*)&Bs[k * 128 + tc * 4];
            float av[8] = {a0.x, a0.y, a0.z, a0.w, a1.x, a1.y, a1.z, a1.w};
            float bv[4] = {b.x, b.y, b.z, b.w};
#pragma unroll
            for (int i = 0; i < 8; ++i)
#pragma unroll
                for (int j = 0; j < 4; ++j) acc[i][j] += av[i] * bv[j];
        }
        __syncthreads();
    }
#pragma unroll
    for (int i = 0; i < 8; ++i) {
        int gr = row0 + r0 + i;
        if (gr < N) {
            float4 v = make_float4(acc[i][0], acc[i][1], acc[i][2], acc[i][3]);
            *(float4*)(hout + (size_t)gr * 128 + tc * 4) = v;
        }
    }
}

// ---------------------------------------------------------------------------
// alpha_src / alpha_dst per (node, head)
// ---------------------------------------------------------------------------
__global__ __launch_bounds__(256) void calc_alpha(const float* __restrict__ h,
                                                  const float* __restrict__ a_src,
                                                  const float* __restrict__ a_dst,
                                                  float* __restrict__ as,
                                                  float* __restrict__ ad, int N) {
    int gid = blockIdx.x * 256 + threadIdx.x;
    int n = gid >> 3;
    int hh = gid & 7;
    if (n >= N) return;
    const float4* hp  = (const float4*)(h + (size_t)n * 128 + hh * 16);
    const float4* asp = (const float4*)(a_src + hh * 16);
    const float4* adp = (const float4*)(a_dst + hh * 16);
    float s = 0.f, d = 0.f;
#pragma unroll
    for (int i = 0; i < 4; ++i) {
        float4 hv = hp[i], av = asp[i], bv = adp[i];
        s += hv.x * av.x + hv.y * av.y + hv.z * av.z + hv.w * av.w;
        d += hv.x * bv.x + hv.y * bv.y + hv.z * bv.z + hv.w * bv.w;
    }
    as[gid] = s;
    ad[gid] = d;
}

// ---------------------------------------------------------------------------
// CSR build: histogram of dst, block-level exclusive scan, place edges
// ---------------------------------------------------------------------------
__global__ __launch_bounds__(256) void hist_dst(const int* __restrict__ ei, int* __restrict__ deg, int E) {
    int e = blockIdx.x * 256 + threadIdx.x;
    if (e >= E) return;
    atomicAdd(&deg[ei[E + e]], 1);
}

__global__ __launch_bounds__(256) void scan_block(const int* __restrict__ deg,
                                                  int* __restrict__ rowptr,
                                                  int* __restrict__ partials, int N) {
    __shared__ int s[256];
    int tid = threadIdx.x;
    int i = blockIdx.x * 256 + tid;
    int v = i < N ? deg[i] : 0;
    s[tid] = v;
    __syncthreads();
#pragma unroll
    for (int off = 1; off < 256; off <<= 1) {
        int t = tid >= off ? s[tid - off] : 0;
        __syncthreads();
        s[tid] += t;
        __syncthreads();
    }
    if (i < N) rowptr[i] = s[tid] - v;       // exclusive within block
    if (tid == 255) partials[blockIdx.x] = s[255];
}

__global__ __launch_bounds__(1024) void scan_partials(int* __restrict__ partials, int nb) {
    __shared__ int s[1024];
    int tid = threadIdx.x;
    int v = tid < nb ? partials[tid] : 0;
    s[tid] = v;
    __syncthreads();
#pragma unroll
    for (int off = 1; off < 1024; off <<= 1) {
        int t = tid >= off ? s[tid - off] : 0;
        __syncthreads();
        s[tid] += t;
        __syncthreads();
    }
    if (tid < nb) partials[tid] = s[tid] - v;  // exclusive
}

__global__ __launch_bounds__(256) void add_offsets(int* __restrict__ rowptr,
                                                   const int* __restrict__ partials, int N) {
    int i = blockIdx.x * 256 + threadIdx.x;
    if (i >= N) return;
    rowptr[i] += partials[blockIdx.x];
}

// place: pos = rowptr[dst]++ (atomic). After this kernel rowptr[i] == row end.
__global__ __launch_bounds__(256) void place_edges(const int* __restrict__ ei,
                                                   int* __restrict__ rowptr,
                                                   int* __restrict__ sortedSrc, int E) {
    int e = blockIdx.x * 256 + threadIdx.x;
    if (e >= E) return;
    int j = ei[e];
    int i = ei[E + e];
    int pos = atomicAdd(&rowptr[i], 1);
    sortedSrc[pos] = j;
}

// ---------------------------------------------------------------------------
// Aggregate: one 64-lane wave per dst node. Lane l handles channels 2l, 2l+1
// (both in head l/8). All 8 lanes of a head compute identical w -> each lane
// keeps its own denom copy, no cross-lane reduce. Writes out exactly once.
// rowptrEnd[i] = end (post-place); start = end - deg[i].
// ---------------------------------------------------------------------------
__global__ __launch_bounds__(256) void aggregate(const int* __restrict__ rowptrEnd,
                                                 const int* __restrict__ deg,
                                                 const int* __restrict__ sortedSrc,
                                                 const float* __restrict__ h,
                                                 const float* __restrict__ as,
                                                 const float* __restrict__ ad,
                                                 const float* __restrict__ bias,
                                                 float* __restrict__ out, int N) {
    int node = blockIdx.x * 4 + (threadIdx.x >> 6);
    int lane = threadIdx.x & 63;
    if (node >= N) return;
    int hh = lane >> 3;
    int end = rowptrEnd[node];
    int start = end - deg[node];
    float adv = ad[node * 8 + hh];

    float accx = 0.f, accy = 0.f, dsum = 0.f;
    int e = start;
    int jn = (e < end) ? sortedSrc[e] : 0;
    while (e < end) {
        int j = jn;
        ++e;
        if (e < end) jn = sortedSrc[e];   // prefetch next src
        float t = as[j * 8 + hh] + adv;
        t = t > 0.f ? t : NEG_SLOPE * t;
        float w = __expf(t);
        float2 hv = *(const float2*)(h + (size_t)j * 128 + lane * 2);
        accx += w * hv.x;
        accy += w * hv.y;
        dsum += w;
    }
    // self-loop
    {
        float t = as[node * 8 + hh] + adv;
        t = t > 0.f ? t : NEG_SLOPE * t;
        float w = __expf(t);
        float2 hv = *(const float2*)(h + (size_t)node * 128 + lane * 2);
        accx += w * hv.x;
        accy += w * hv.y;
        dsum += w;
    }
    float inv = 1.0f / (dsum + 1e-16f);
    float ox = accx * inv + bias[lane * 2];
    float oy = accy * inv + bias[lane * 2 + 1];
    ox = ox > 0.f ? ox : 0.f;
    oy = oy > 0.f ? oy : 0.f;
    *(float2*)(out + (size_t)node * 128 + lane * 2) = make_float2(ox, oy);
}

extern "C" void kernel_launch(void* const* d_in, const int* in_sizes, int n_in,
                              void* d_out, int out_size, void* d_ws, size_t ws_size,
                              hipStream_t stream) {
    const float* x     = (const float*)d_in[0];
    const int*   ei    = (const int*)d_in[1];
    const float* W     = (const float*)d_in[2];
    const float* a_src = (const float*)d_in[3];
    const float* a_dst = (const float*)d_in[4];
    const float* bias  = (const float*)d_in[5];
    float* out = (float*)d_out;

    const int N = in_sizes[0] / 128;   // 100000
    const int E = in_sizes[1] / 2;     // 1600000
    const int NB = (N + 255) / 256;    // scan blocks (391)

    char* ws = (char*)d_ws;
    size_t off = 0;
    float* h         = (float*)(ws + off); off += (size_t)N * 128 * 4;  // 51.2 MB
    float* as        = (float*)(ws + off); off += (size_t)N * 8 * 4;    // 3.2 MB
    float* ad        = (float*)(ws + off); off += (size_t)N * 8 * 4;    // 3.2 MB
    int*   sortedSrc = (int*)(ws + off);   off += (size_t)E * 4;        // 6.4 MB
    int*   deg       = (int*)(ws + off);   off += (size_t)N * 4;        // 0.4 MB
    int*   rowptr    = (int*)(ws + off);   off += (size_t)N * 4;        // 0.4 MB
    int*   partials  = (int*)(ws + off);   off += (size_t)NB * 4;

    hipMemsetAsync(deg, 0, (size_t)N * 4, stream);

    // CSR build
    hist_dst<<<(E + 255) / 256, 256, 0, stream>>>(ei, deg, E);
    scan_block<<<NB, 256, 0, stream>>>(deg, rowptr, partials, N);
    scan_partials<<<1, 1024, 0, stream>>>(partials, NB);
    add_offsets<<<NB, 256, 0, stream>>>(rowptr, partials, N);
    place_edges<<<(E + 255) / 256, 256, 0, stream>>>(ei, rowptr, sortedSrc, E);

    // Dense compute
    gemm_h<<<(N + 63) / 64, 256, 0, stream>>>(x, W, h, N);
    calc_alpha<<<(N * 8 + 255) / 256, 256, 0, stream>>>(h, a_src, a_dst, as, ad, N);

    // Gather aggregation (rowptr now holds row ends)
    aggregate<<<(N + 3) / 4, 256, 0, stream>>>(rowptr, deg, sortedSrc, h, as, ad, bias, out, N);
}

// Round 3
// 455.289 us; speedup vs baseline: 6.4661x; 1.0649x over previous
//
#include <hip/hip_runtime.h>
#include <hip/hip_bf16.h>

#define NEG_SLOPE 0.2f

struct alignas(8) bf16x4 { __hip_bfloat16 v[4]; };

// ---------------------------------------------------------------------------
// GEMM: h[N,128] = x[N,128] @ W[128,128]; fp32 accumulate, bf16 store.
// ---------------------------------------------------------------------------
__global__ __launch_bounds__(256) void gemm_h(const float* __restrict__ x,
                                              const float* __restrict__ Wm,
                                              __hip_bfloat16* __restrict__ hout, int N) {
    __shared__ float As[32][68];
    __shared__ float Bs[32 * 128];

    const int tid  = threadIdx.x;
    const int row0 = blockIdx.x * 64;
    const int tr   = tid >> 5;
    const int tc   = tid & 31;
    const int r0   = tr * 8;

    float acc[8][4];
#pragma unroll
    for (int i = 0; i < 8; ++i)
#pragma unroll
        for (int j = 0; j < 4; ++j) acc[i][j] = 0.f;

    for (int kc = 0; kc < 4; ++kc) {
        const int k0 = kc * 32;
#pragma unroll
        for (int p = 0; p < 2; ++p) {
            int lr = (tid >> 3) + p * 32;
            int lk = (tid & 7) * 4;
            int gr = row0 + lr;
            int grc = gr < N ? gr : N - 1;
            float4 v = *(const float4*)(x + (size_t)grc * 128 + k0 + lk);
            As[lk + 0][lr] = v.x;
            As[lk + 1][lr] = v.y;
            As[lk + 2][lr] = v.z;
            As[lk + 3][lr] = v.w;
        }
#pragma unroll
        for (int p = 0; p < 4; ++p) {
            int idx = p * 1024 + tid * 4;
            *(float4*)&Bs[idx] = *(const float4*)(Wm + k0 * 128 + idx);
        }
        __syncthreads();
#pragma unroll
        for (int k = 0; k < 32; ++k) {
            float4 a0 = *(const float4*)&As[k][r0];
            float4 a1 = *(const float4*)&As[k][r0 + 4];
            float4 b  = *(const float4*)&Bs[k * 128 + tc * 4];
            float av[8] = {a0.x, a0.y, a0.z, a0.w, a1.x, a1.y, a1.z, a1.w};
            float bv[4] = {b.x, b.y, b.z, b.w};
#pragma unroll
            for (int i = 0; i < 8; ++i)
#pragma unroll
                for (int j = 0; j < 4; ++j) acc[i][j] += av[i] * bv[j];
        }
        __syncthreads();
    }
#pragma unroll
    for (int i = 0; i < 8; ++i) {
        int gr = row0 + r0 + i;
        if (gr < N) {
            bf16x4 o;
            o.v[0] = __float2bfloat16(acc[i][0]);
            o.v[1] = __float2bfloat16(acc[i][1]);
            o.v[2] = __float2bfloat16(acc[i][2]);
            o.v[3] = __float2bfloat16(acc[i][3]);
            *(bf16x4*)(hout + (size_t)gr * 128 + tc * 4) = o;
        }
    }
}

// ---------------------------------------------------------------------------
// alpha_src / alpha_dst per (node, head), bf16 h input
// ---------------------------------------------------------------------------
__global__ __launch_bounds__(256) void calc_alpha(const __hip_bfloat16* __restrict__ h,
                                                  const float* __restrict__ a_src,
                                                  const float* __restrict__ a_dst,
                                                  float* __restrict__ as,
                                                  float* __restrict__ ad, int N) {
    int gid = blockIdx.x * 256 + threadIdx.x;
    int n = gid >> 3;
    int hh = gid & 7;
    if (n >= N) return;
    const bf16x4* hp  = (const bf16x4*)(h + (size_t)n * 128 + hh * 16);
    const float4* asp = (const float4*)(a_src + hh * 16);
    const float4* adp = (const float4*)(a_dst + hh * 16);
    float s = 0.f, d = 0.f;
#pragma unroll
    for (int i = 0; i < 4; ++i) {
        bf16x4 hv = hp[i];
        float4 av = asp[i], bv = adp[i];
        float f0 = __bfloat162float(hv.v[0]);
        float f1 = __bfloat162float(hv.v[1]);
        float f2 = __bfloat162float(hv.v[2]);
        float f3 = __bfloat162float(hv.v[3]);
        s += f0 * av.x + f1 * av.y + f2 * av.z + f3 * av.w;
        d += f0 * bv.x + f1 * bv.y + f2 * bv.z + f3 * bv.w;
    }
    as[gid] = s;
    ad[gid] = d;
}

// ---------------------------------------------------------------------------
// CSR build
// ---------------------------------------------------------------------------
__global__ __launch_bounds__(256) void hist_dst(const int* __restrict__ ei, int* __restrict__ deg, int E) {
    int base = (blockIdx.x * 256 + threadIdx.x) * 4;
    if (base + 3 < E) {
        int4 d = *(const int4*)(ei + E + base);
        atomicAdd(&deg[d.x], 1);
        atomicAdd(&deg[d.y], 1);
        atomicAdd(&deg[d.z], 1);
        atomicAdd(&deg[d.w], 1);
    } else {
        for (int e = base; e < E; ++e) atomicAdd(&deg[ei[E + e]], 1);
    }
}

__global__ __launch_bounds__(256) void scan_block(const int* __restrict__ deg,
                                                  int* __restrict__ rowptr,
                                                  int* __restrict__ partials, int N) {
    __shared__ int s[256];
    int tid = threadIdx.x;
    int i = blockIdx.x * 256 + tid;
    int v = i < N ? deg[i] : 0;
    s[tid] = v;
    __syncthreads();
#pragma unroll
    for (int off = 1; off < 256; off <<= 1) {
        int t = tid >= off ? s[tid - off] : 0;
        __syncthreads();
        s[tid] += t;
        __syncthreads();
    }
    if (i < N) rowptr[i] = s[tid] - v;
    if (tid == 255) partials[blockIdx.x] = s[255];
}

__global__ __launch_bounds__(1024) void scan_partials(int* __restrict__ partials, int nb) {
    __shared__ int s[1024];
    int tid = threadIdx.x;
    int v = tid < nb ? partials[tid] : 0;
    s[tid] = v;
    __syncthreads();
#pragma unroll
    for (int off = 1; off < 1024; off <<= 1) {
        int t = tid >= off ? s[tid - off] : 0;
        __syncthreads();
        s[tid] += t;
        __syncthreads();
    }
    if (tid < nb) partials[tid] = s[tid] - v;
}

__global__ __launch_bounds__(256) void add_offsets(int* __restrict__ rowptr,
                                                   const int* __restrict__ partials, int N) {
    int i = blockIdx.x * 256 + threadIdx.x;
    if (i >= N) return;
    rowptr[i] += partials[blockIdx.x];
}

__global__ __launch_bounds__(256) void place_edges(const int* __restrict__ ei,
                                                   int* __restrict__ rowptr,
                                                   int* __restrict__ sortedSrc, int E) {
    int e = blockIdx.x * 256 + threadIdx.x;
    if (e >= E) return;
    int j = ei[e];
    int i = ei[E + e];
    int pos = atomicAdd(&rowptr[i], 1);
    sortedSrc[pos] = j;
}

// ---------------------------------------------------------------------------
// Aggregate: one wave per dst node; lane l handles channels 2l,2l+1 (head l>>3).
// bf16 h gather, fp32 accumulate, 2-edge unroll for MLP.
// ---------------------------------------------------------------------------
__global__ __launch_bounds__(256) void aggregate(const int* __restrict__ rowptrEnd,
                                                 const int* __restrict__ deg,
                                                 const int* __restrict__ sortedSrc,
                                                 const __hip_bfloat16* __restrict__ h,
                                                 const float* __restrict__ as,
                                                 const float* __restrict__ ad,
                                                 const float* __restrict__ bias,
                                                 float* __restrict__ out, int N) {
    int node = blockIdx.x * 4 + (threadIdx.x >> 6);
    int lane = threadIdx.x & 63;
    if (node >= N) return;
    int hh = lane >> 3;
    int end = rowptrEnd[node];
    int start = end - deg[node];
    float adv = ad[node * 8 + hh];

    float accx = 0.f, accy = 0.f, dsum = 0.f;
    int e = start;
    for (; e + 1 < end; e += 2) {
        int j0 = sortedSrc[e];
        int j1 = sortedSrc[e + 1];
        float as0 = as[j0 * 8 + hh];
        float as1 = as[j1 * 8 + hh];
        __hip_bfloat162 h0 = *(const __hip_bfloat162*)(h + (size_t)j0 * 128 + lane * 2);
        __hip_bfloat162 h1 = *(const __hip_bfloat162*)(h + (size_t)j1 * 128 + lane * 2);
        float t0 = as0 + adv; t0 = t0 > 0.f ? t0 : NEG_SLOPE * t0;
        float t1 = as1 + adv; t1 = t1 > 0.f ? t1 : NEG_SLOPE * t1;
        float w0 = __expf(t0);
        float w1 = __expf(t1);
        accx += w0 * __bfloat162float(h0.x) + w1 * __bfloat162float(h1.x);
        accy += w0 * __bfloat162float(h0.y) + w1 * __bfloat162float(h1.y);
        dsum += w0 + w1;
    }
    if (e < end) {
        int j = sortedSrc[e];
        float t = as[j * 8 + hh] + adv;
        t = t > 0.f ? t : NEG_SLOPE * t;
        float w = __expf(t);
        __hip_bfloat162 hv = *(const __hip_bfloat162*)(h + (size_t)j * 128 + lane * 2);
        accx += w * __bfloat162float(hv.x);
        accy += w * __bfloat162float(hv.y);
        dsum += w;
    }
    // self-loop
    {
        float t = as[node * 8 + hh] + adv;
        t = t > 0.f ? t : NEG_SLOPE * t;
        float w = __expf(t);
        __hip_bfloat162 hv = *(const __hip_bfloat162*)(h + (size_t)node * 128 + lane * 2);
        accx += w * __bfloat162float(hv.x);
        accy += w * __bfloat162float(hv.y);
        dsum += w;
    }
    float inv = 1.0f / (dsum + 1e-16f);
    float ox = accx * inv + bias[lane * 2];
    float oy = accy * inv + bias[lane * 2 + 1];
    ox = ox > 0.f ? ox : 0.f;
    oy = oy > 0.f ? oy : 0.f;
    *(float2*)(out + (size_t)node * 128 + lane * 2) = make_float2(ox, oy);
}

extern "C" void kernel_launch(void* const* d_in, const int* in_sizes, int n_in,
                              void* d_out, int out_size, void* d_ws, size_t ws_size,
                              hipStream_t stream) {
    const float* x     = (const float*)d_in[0];
    const int*   ei    = (const int*)d_in[1];
    const float* W     = (const float*)d_in[2];
    const float* a_src = (const float*)d_in[3];
    const float* a_dst = (const float*)d_in[4];
    const float* bias  = (const float*)d_in[5];
    float* out = (float*)d_out;

    const int N = in_sizes[0] / 128;   // 100000
    const int E = in_sizes[1] / 2;     // 1600000
    const int NB = (N + 255) / 256;

    char* ws = (char*)d_ws;
    size_t off = 0;
    __hip_bfloat16* h = (__hip_bfloat16*)(ws + off); off += (size_t)N * 128 * 2;  // 25.6 MB
    float* as        = (float*)(ws + off); off += (size_t)N * 8 * 4;
    float* ad        = (float*)(ws + off); off += (size_t)N * 8 * 4;
    int*   sortedSrc = (int*)(ws + off);   off += (size_t)E * 4;
    int*   deg       = (int*)(ws + off);   off += (size_t)N * 4;
    int*   rowptr    = (int*)(ws + off);   off += (size_t)N * 4;
    int*   partials  = (int*)(ws + off);   off += (size_t)NB * 4;

    hipMemsetAsync(deg, 0, (size_t)N * 4, stream);

    // CSR build
    hist_dst<<<(E / 4 + 255) / 256, 256, 0, stream>>>(ei, deg, E);
    scan_block<<<NB, 256, 0, stream>>>(deg, rowptr, partials, N);
    scan_partials<<<1, 1024, 0, stream>>>(partials, NB);
    add_offsets<<<NB, 256, 0, stream>>>(rowptr, partials, N);
    place_edges<<<(E + 255) / 256, 256, 0, stream>>>(ei, rowptr, sortedSrc, E);

    // Dense compute
    gemm_h<<<(N + 63) / 64, 256, 0, stream>>>(x, W, h, N);
    calc_alpha<<<(N * 8 + 255) / 256, 256, 0, stream>>>(h, a_src, a_dst, as, ad, N);

    // Gather aggregation (rowptr now holds row ends)
    aggregate<<<(N + 3) / 4, 256, 0, stream>>>(rowptr, deg, sortedSrc, h, as, ad, bias, out, N);
}

// Round 4
// 278.851 us; speedup vs baseline: 10.5574x; 1.6327x over previous
//
#include <hip/hip_runtime.h>
#include <hip/hip_bf16.h>

#define NEG_SLOPE 0.2f
#define NBUCK 391      // ceil(100000 / 256) buckets of 256 dst nodes
#define ABLK 8192      // edges per bucket_edges block
#define EPT 16         // edges per thread (512 threads)

struct alignas(8) bf16x4 { __hip_bfloat16 v[4]; };

// ---------------------------------------------------------------------------
// GEMM: h[N,128] = x[N,128] @ W[128,128]; fp32 accumulate, bf16 store.
// ---------------------------------------------------------------------------
__global__ __launch_bounds__(256) void gemm_h(const float* __restrict__ x,
                                              const float* __restrict__ Wm,
                                              __hip_bfloat16* __restrict__ hout, int N) {
    __shared__ float As[32][68];
    __shared__ float Bs[32 * 128];

    const int tid  = threadIdx.x;
    const int row0 = blockIdx.x * 64;
    const int tr   = tid >> 5;
    const int tc   = tid & 31;
    const int r0   = tr * 8;

    float acc[8][4];
#pragma unroll
    for (int i = 0; i < 8; ++i)
#pragma unroll
        for (int j = 0; j < 4; ++j) acc[i][j] = 0.f;

    for (int kc = 0; kc < 4; ++kc) {
        const int k0 = kc * 32;
#pragma unroll
        for (int p = 0; p < 2; ++p) {
            int lr = (tid >> 3) + p * 32;
            int lk = (tid & 7) * 4;
            int gr = row0 + lr;
            int grc = gr < N ? gr : N - 1;
            float4 v = *(const float4*)(x + (size_t)grc * 128 + k0 + lk);
            As[lk + 0][lr] = v.x;
            As[lk + 1][lr] = v.y;
            As[lk + 2][lr] = v.z;
            As[lk + 3][lr] = v.w;
        }
#pragma unroll
        for (int p = 0; p < 4; ++p) {
            int idx = p * 1024 + tid * 4;
            *(float4*)&Bs[idx] = *(const float4*)(Wm + k0 * 128 + idx);
        }
        __syncthreads();
#pragma unroll
        for (int k = 0; k < 32; ++k) {
            float4 a0 = *(const float4*)&As[k][r0];
            float4 a1 = *(const float4*)&As[k][r0 + 4];
            float4 b  = *(const float4*)&Bs[k * 128 + tc * 4];
            float av[8] = {a0.x, a0.y, a0.z, a0.w, a1.x, a1.y, a1.z, a1.w};
            float bv[4] = {b.x, b.y, b.z, b.w};
#pragma unroll
            for (int i = 0; i < 8; ++i)
#pragma unroll
                for (int j = 0; j < 4; ++j) acc[i][j] += av[i] * bv[j];
        }
        __syncthreads();
    }
#pragma unroll
    for (int i = 0; i < 8; ++i) {
        int gr = row0 + r0 + i;
        if (gr < N) {
            bf16x4 o;
            o.v[0] = __float2bfloat16(acc[i][0]);
            o.v[1] = __float2bfloat16(acc[i][1]);
            o.v[2] = __float2bfloat16(acc[i][2]);
            o.v[3] = __float2bfloat16(acc[i][3]);
            *(bf16x4*)(hout + (size_t)gr * 128 + tc * 4) = o;
        }
    }
}

// ---------------------------------------------------------------------------
// alpha_src / alpha_dst per (node, head), bf16 h input
// ---------------------------------------------------------------------------
__global__ __launch_bounds__(256) void calc_alpha(const __hip_bfloat16* __restrict__ h,
                                                  const float* __restrict__ a_src,
                                                  const float* __restrict__ a_dst,
                                                  float* __restrict__ as,
                                                  float* __restrict__ ad, int N) {
    int gid = blockIdx.x * 256 + threadIdx.x;
    int n = gid >> 3;
    int hh = gid & 7;
    if (n >= N) return;
    const bf16x4* hp  = (const bf16x4*)(h + (size_t)n * 128 + hh * 16);
    const float4* asp = (const float4*)(a_src + hh * 16);
    const float4* adp = (const float4*)(a_dst + hh * 16);
    float s = 0.f, d = 0.f;
#pragma unroll
    for (int i = 0; i < 4; ++i) {
        bf16x4 hv = hp[i];
        float4 av = asp[i], bv = adp[i];
        float f0 = __bfloat162float(hv.v[0]);
        float f1 = __bfloat162float(hv.v[1]);
        float f2 = __bfloat162float(hv.v[2]);
        float f3 = __bfloat162float(hv.v[3]);
        s += f0 * av.x + f1 * av.y + f2 * av.z + f3 * av.w;
        d += f0 * bv.x + f1 * bv.y + f2 * bv.z + f3 * bv.w;
    }
    as[gid] = s;
    ad[gid] = d;
}

// ---------------------------------------------------------------------------
// Phase A: bucket edges. Each block stages ABLK edges in LDS, histograms over
// NBUCK buckets (dst>>8), LDS-scans, writes edges grouped-by-bucket to its own
// slab (64KB window scatter -> line-friendly) + per-(block,bucket) cnt/start.
// ---------------------------------------------------------------------------
__global__ __launch_bounds__(512) void bucket_edges(const int* __restrict__ ei, int E,
                                                    uint2* __restrict__ slab,
                                                    int* __restrict__ cntG,
                                                    int* __restrict__ startG) {
    __shared__ int sS[ABLK];
    __shared__ int dS[ABLK];
    __shared__ int hist[512];
    __shared__ int cur[NBUCK];
    const int t = threadIdx.x;
    const int blk = blockIdx.x;
    const int base = blk * ABLK;
    int count = E - base; if (count > ABLK) count = ABLK;

    hist[t] = 0;
#pragma unroll
    for (int k = 0; k < EPT; ++k) {
        int i = k * 512 + t;
        int idx = base + i;
        if (i < count) { sS[i] = ei[idx]; dS[i] = ei[E + idx]; }
    }
    __syncthreads();
#pragma unroll
    for (int k = 0; k < EPT; ++k) {
        int i = k * 512 + t;
        if (i < count) atomicAdd(&hist[dS[i] >> 8], 1);
    }
    __syncthreads();
    int v = hist[t];
    for (int off = 1; off < 512; off <<= 1) {
        int u = t >= off ? hist[t - off] : 0;
        __syncthreads();
        hist[t] += u;
        __syncthreads();
    }
    int excl = hist[t] - v;
    if (t < NBUCK) {
        cntG[blk * NBUCK + t]   = v;
        startG[blk * NBUCK + t] = excl;
        cur[t] = excl;
    }
    __syncthreads();
#pragma unroll
    for (int k = 0; k < EPT; ++k) {
        int i = k * 512 + t;
        if (i < count) {
            int d = dS[i];
            int pos = atomicAdd(&cur[d >> 8], 1);
            slab[(size_t)blk * ABLK + pos] = make_uint2((unsigned)sS[i], (unsigned)d);
        }
    }
}

// ---------------------------------------------------------------------------
// Column totals of cnt matrix: total[b] = sum over blocks.
// ---------------------------------------------------------------------------
__global__ __launch_bounds__(64) void bucket_totals(const int* __restrict__ cntG, int nblk,
                                                    int* __restrict__ totalG) {
    int b = blockIdx.x;
    int lane = threadIdx.x;
    int s = 0;
    for (int blk = lane; blk < nblk; blk += 64) s += cntG[blk * NBUCK + b];
#pragma unroll
    for (int off = 32; off > 0; off >>= 1) s += __shfl_down(s, off);
    if (lane == 0) totalG[b] = s;
}

// ---------------------------------------------------------------------------
// Exclusive scan of bucket totals -> bucketStart[0..NBUCK] (last = E).
// ---------------------------------------------------------------------------
__global__ __launch_bounds__(512) void scan_buckets(const int* __restrict__ totalG,
                                                    int* __restrict__ bucketStart) {
    __shared__ int s[512];
    int t = threadIdx.x;
    int v = t < NBUCK ? totalG[t] : 0;
    s[t] = v;
    __syncthreads();
    for (int off = 1; off < 512; off <<= 1) {
        int u = t >= off ? s[t - off] : 0;
        __syncthreads();
        s[t] += u;
        __syncthreads();
    }
    int excl = s[t] - v;
    if (t <= NBUCK) bucketStart[t] = excl;
}

// ---------------------------------------------------------------------------
// Phase B: per bucket, gather its slab segments into LDS, LDS dst-histogram +
// scan -> write rowptr directly; place sortedSrc with LDS rank counters
// (scatter confined to the bucket's ~16KB output window).
// ---------------------------------------------------------------------------
__global__ __launch_bounds__(512) void build_csr(const uint2* __restrict__ slab,
                                                 const int* __restrict__ cntG,
                                                 const int* __restrict__ startG,
                                                 const int* __restrict__ bucketStart,
                                                 int nblk, int N, int E,
                                                 int* __restrict__ rowptr,
                                                 int* __restrict__ sortedSrc) {
    __shared__ uint2 eL[ABLK];
    __shared__ int scanArr[512];
    __shared__ int hist[512];
    __shared__ int lp[256];
    const int b = blockIdx.x;
    const int t = threadIdx.x;
    const int nodeBase = b << 8;

    int c = 0, st = 0;
    if (t < nblk) { c = cntG[t * NBUCK + b]; st = startG[t * NBUCK + b]; }
    hist[t] = 0;
    scanArr[t] = c;
    __syncthreads();
    for (int off = 1; off < 512; off <<= 1) {
        int u = t >= off ? scanArr[t - off] : 0;
        __syncthreads();
        scanArr[t] += u;
        __syncthreads();
    }
    const int total = scanArr[511];
    const int myoff = scanArr[t] - c;
    // gather segments into LDS
    if (t < nblk && c > 0) {
        const uint2* p = slab + (size_t)t * ABLK + st;
        for (int i = 0; i < c; ++i) eL[myoff + i] = p[i];
    }
    __syncthreads();
    // histogram over local dst
    for (int e = t; e < total; e += 512) atomicAdd(&hist[eL[e].y & 255], 1);
    __syncthreads();
    int hv = hist[t];
    for (int off = 1; off < 512; off <<= 1) {
        int u = t >= off ? hist[t - off] : 0;
        __syncthreads();
        hist[t] += u;
        __syncthreads();
    }
    int hexcl = hist[t] - hv;
    const int bs = bucketStart[b];
    int nodes = N - nodeBase; if (nodes > 256) nodes = 256;
    if (t < nodes) rowptr[nodeBase + t] = bs + hexcl;
    if (t < 256) lp[t] = hexcl;
    if (b == gridDim.x - 1 && t == 0) rowptr[N] = E;
    __syncthreads();
    // place
    for (int e = t; e < total; e += 512) {
        uint2 ed = eL[e];
        int pos = atomicAdd(&lp[ed.y & 255], 1);
        sortedSrc[bs + pos] = (int)ed.x;
    }
}

// ---------------------------------------------------------------------------
// Aggregate: one wave per dst node; lane l handles channels 2l,2l+1 (head l>>3).
// bf16 h gather, fp32 accumulate, 4-edge unroll.
// ---------------------------------------------------------------------------
__global__ __launch_bounds__(256) void aggregate(const int* __restrict__ rowptr,
                                                 const int* __restrict__ sortedSrc,
                                                 const __hip_bfloat16* __restrict__ h,
                                                 const float* __restrict__ as,
                                                 const float* __restrict__ ad,
                                                 const float* __restrict__ bias,
                                                 float* __restrict__ out, int N) {
    int node = blockIdx.x * 4 + (threadIdx.x >> 6);
    int lane = threadIdx.x & 63;
    if (node >= N) return;
    int hh = lane >> 3;
    int start = rowptr[node];
    int end = rowptr[node + 1];
    float adv = ad[node * 8 + hh];

    float accx = 0.f, accy = 0.f, dsum = 0.f;
    int e = start;
    for (; e + 3 < end; e += 4) {
        int j0 = sortedSrc[e];
        int j1 = sortedSrc[e + 1];
        int j2 = sortedSrc[e + 2];
        int j3 = sortedSrc[e + 3];
        float a0 = as[j0 * 8 + hh];
        float a1 = as[j1 * 8 + hh];
        float a2 = as[j2 * 8 + hh];
        float a3 = as[j3 * 8 + hh];
        __hip_bfloat162 h0 = *(const __hip_bfloat162*)(h + (size_t)j0 * 128 + lane * 2);
        __hip_bfloat162 h1 = *(const __hip_bfloat162*)(h + (size_t)j1 * 128 + lane * 2);
        __hip_bfloat162 h2 = *(const __hip_bfloat162*)(h + (size_t)j2 * 128 + lane * 2);
        __hip_bfloat162 h3 = *(const __hip_bfloat162*)(h + (size_t)j3 * 128 + lane * 2);
        float t0 = a0 + adv; t0 = t0 > 0.f ? t0 : NEG_SLOPE * t0;
        float t1 = a1 + adv; t1 = t1 > 0.f ? t1 : NEG_SLOPE * t1;
        float t2 = a2 + adv; t2 = t2 > 0.f ? t2 : NEG_SLOPE * t2;
        float t3 = a3 + adv; t3 = t3 > 0.f ? t3 : NEG_SLOPE * t3;
        float w0 = __expf(t0), w1 = __expf(t1), w2 = __expf(t2), w3 = __expf(t3);
        accx += w0 * __bfloat162float(h0.x) + w1 * __bfloat162float(h1.x)
              + w2 * __bfloat162float(h2.x) + w3 * __bfloat162float(h3.x);
        accy += w0 * __bfloat162float(h0.y) + w1 * __bfloat162float(h1.y)
              + w2 * __bfloat162float(h2.y) + w3 * __bfloat162float(h3.y);
        dsum += (w0 + w1) + (w2 + w3);
    }
    for (; e < end; ++e) {
        int j = sortedSrc[e];
        float t = as[j * 8 + hh] + adv;
        t = t > 0.f ? t : NEG_SLOPE * t;
        float w = __expf(t);
        __hip_bfloat162 hv = *(const __hip_bfloat162*)(h + (size_t)j * 128 + lane * 2);
        accx += w * __bfloat162float(hv.x);
        accy += w * __bfloat162float(hv.y);
        dsum += w;
    }
    // self-loop
    {
        float t = as[node * 8 + hh] + adv;
        t = t > 0.f ? t : NEG_SLOPE * t;
        float w = __expf(t);
        __hip_bfloat162 hv = *(const __hip_bfloat162*)(h + (size_t)node * 128 + lane * 2);
        accx += w * __bfloat162float(hv.x);
        accy += w * __bfloat162float(hv.y);
        dsum += w;
    }
    float inv = 1.0f / (dsum + 1e-16f);
    float ox = accx * inv + bias[lane * 2];
    float oy = accy * inv + bias[lane * 2 + 1];
    ox = ox > 0.f ? ox : 0.f;
    oy = oy > 0.f ? oy : 0.f;
    *(float2*)(out + (size_t)node * 128 + lane * 2) = make_float2(ox, oy);
}

extern "C" void kernel_launch(void* const* d_in, const int* in_sizes, int n_in,
                              void* d_out, int out_size, void* d_ws, size_t ws_size,
                              hipStream_t stream) {
    const float* x     = (const float*)d_in[0];
    const int*   ei    = (const int*)d_in[1];
    const float* W     = (const float*)d_in[2];
    const float* a_src = (const float*)d_in[3];
    const float* a_dst = (const float*)d_in[4];
    const float* bias  = (const float*)d_in[5];
    float* out = (float*)d_out;

    const int N = in_sizes[0] / 128;   // 100000
    const int E = in_sizes[1] / 2;     // 1600000
    const int nblk = (E + ABLK - 1) / ABLK;  // 196

    char* ws = (char*)d_ws;
    size_t off = 0;
    auto alloc = [&](size_t bytes) { void* p = ws + off; off = (off + bytes + 255) & ~(size_t)255; return p; };
    __hip_bfloat16* h  = (__hip_bfloat16*)alloc((size_t)N * 128 * 2);
    float* as          = (float*)alloc((size_t)N * 8 * 4);
    float* ad          = (float*)alloc((size_t)N * 8 * 4);
    int*   sortedSrc   = (int*)alloc((size_t)E * 4);
    int*   rowptr      = (int*)alloc((size_t)(N + 1) * 4);
    uint2* slab        = (uint2*)alloc((size_t)nblk * ABLK * 8);
    int*   cntG        = (int*)alloc((size_t)nblk * NBUCK * 4);
    int*   startG      = (int*)alloc((size_t)nblk * NBUCK * 4);
    int*   totalG      = (int*)alloc((size_t)NBUCK * 4);
    int*   bucketSt    = (int*)alloc((size_t)(NBUCK + 1) * 4);

    // CSR build (no global atomics, localized scatters)
    bucket_edges<<<nblk, 512, 0, stream>>>(ei, E, slab, cntG, startG);
    bucket_totals<<<NBUCK, 64, 0, stream>>>(cntG, nblk, totalG);
    scan_buckets<<<1, 512, 0, stream>>>(totalG, bucketSt);
    build_csr<<<NBUCK, 512, 0, stream>>>(slab, cntG, startG, bucketSt, nblk, N, E, rowptr, sortedSrc);

    // Dense compute
    gemm_h<<<(N + 63) / 64, 256, 0, stream>>>(x, W, h, N);
    calc_alpha<<<(N * 8 + 255) / 256, 256, 0, stream>>>(h, a_src, a_dst, as, ad, N);

    // Gather aggregation
    aggregate<<<(N + 3) / 4, 256, 0, stream>>>(rowptr, sortedSrc, h, as, ad, bias, out, N);
}

// Round 5
// 255.480 us; speedup vs baseline: 11.5231x; 1.0915x over previous
//
#include <hip/hip_runtime.h>
#include <hip/hip_bf16.h>

#define NEG_SLOPE 0.2f
#define NBUCK 391      // ceil(100000 / 256) buckets of 256 dst nodes
#define ABLK 8192      // edges per bucket_edges block
#define EPT 16         // edges per thread (512 threads)

typedef __attribute__((ext_vector_type(8))) short bf16x8v;
typedef __attribute__((ext_vector_type(4))) float f32x4;

__device__ __forceinline__ unsigned f2bf_bits(float f) {
    unsigned u = __float_as_uint(f);
    return (u + 0x7fffu + ((u >> 16) & 1u)) >> 16;   // RNE fp32 -> bf16 bits
}
__device__ __forceinline__ float bflo(unsigned u) { return __uint_as_float(u << 16); }
__device__ __forceinline__ float bfhi(unsigned u) { return __uint_as_float(u & 0xffff0000u); }

// ---------------------------------------------------------------------------
// prep_w: W[128k][128n] fp32 -> WtG[n][k] bf16 bits (transposed, for B-frags)
// ---------------------------------------------------------------------------
__global__ __launch_bounds__(256) void prep_w(const float* __restrict__ W,
                                              short* __restrict__ WtG) {
    int id = blockIdx.x * 256 + threadIdx.x;   // 16384 total
    int n = id >> 7, k = id & 127;
    WtG[id] = (short)f2bf_bits(W[k * 128 + n]);
}

// ---------------------------------------------------------------------------
// MFMA GEMM: h[N,128] = bf16(x) @ bf16(W), fp32 acc, bf16 h out.
// Fused epilogue computes as/ad per (row, head) from the fp32 accumulator.
// Block: 256 thr = 4 waves, 64 rows. Wave: 16 rows x 128 cols = 8 MFMA tiles.
// Frag layouts (m89/m120-verified): A/B lane holds [m|n=lane&15][k=quad*8+j];
// C/D: col=lane&15, row=quad*4+reg. Col-tile c == head c (16 cols = head_dim).
// ---------------------------------------------------------------------------
__global__ __launch_bounds__(256) void gemm_mfma(const float* __restrict__ x,
                                                 const short* __restrict__ WtG,
                                                 const float* __restrict__ a_src,
                                                 const float* __restrict__ a_dst,
                                                 short* __restrict__ hout,
                                                 float* __restrict__ as,
                                                 float* __restrict__ ad, int N) {
    __shared__ short xs[64 * 136];    // [row][k], stride 136 (16B-aligned rows)
    __shared__ short wt[128 * 136];   // [n][k]
    const int tid = threadIdx.x;
    const int r0 = blockIdx.x * 64;

    // stage Wt (bf16, already transposed in global)
#pragma unroll
    for (int p = 0; p < 8; ++p) {
        int idx = p * 256 + tid;
        int n = idx >> 4, kk = (idx & 15) * 8;
        *(uint4*)&wt[n * 136 + kk] = *(const uint4*)(WtG + n * 128 + kk);
    }
    // stage x: fp32 -> bf16
#pragma unroll
    for (int p = 0; p < 8; ++p) {
        int lin = p * 1024 + tid * 4;
        int row = lin >> 7, k = lin & 127;
        int gr = r0 + row;
        int grc = gr < N ? gr : N - 1;
        float4 v = *(const float4*)(x + (size_t)grc * 128 + k);
        unsigned p0 = f2bf_bits(v.x) | (f2bf_bits(v.y) << 16);
        unsigned p1 = f2bf_bits(v.z) | (f2bf_bits(v.w) << 16);
        *(uint2*)&xs[row * 136 + k] = make_uint2(p0, p1);
    }
    __syncthreads();

    const int wv = tid >> 6;
    const int lane = tid & 63;
    const int lc = lane & 15, quad = lane >> 4;
    f32x4 acc[8];
#pragma unroll
    for (int c = 0; c < 8; ++c) acc[c] = (f32x4){0.f, 0.f, 0.f, 0.f};
    const short* aB = &xs[(wv * 16 + lc) * 136 + quad * 8];
    const short* bB = &wt[lc * 136 + quad * 8];
#pragma unroll
    for (int kc = 0; kc < 4; ++kc) {
        bf16x8v af = *(const bf16x8v*)(aB + kc * 32);
#pragma unroll
        for (int c = 0; c < 8; ++c) {
            bf16x8v bf = *(const bf16x8v*)(bB + c * (16 * 136) + kc * 32);
            acc[c] = __builtin_amdgcn_mfma_f32_16x16x32_bf16(af, bf, acc[c], 0, 0, 0);
        }
    }

    // epilogue: bf16 h store + fused alpha dots
    const int rowb = r0 + wv * 16 + quad * 4;
#pragma unroll
    for (int c = 0; c < 8; ++c) {
        float asc = a_src[c * 16 + lc];
        float adc = a_dst[c * 16 + lc];
        float sv[4], dv[4];
#pragma unroll
        for (int r = 0; r < 4; ++r) {
            float hv = acc[c][r];
            int row = rowb + r;
            if (row < N) hout[(size_t)row * 128 + c * 16 + lc] = (short)f2bf_bits(hv);
            sv[r] = hv * asc;
            dv[r] = hv * adc;
        }
#pragma unroll
        for (int m = 1; m <= 8; m <<= 1) {
#pragma unroll
            for (int r = 0; r < 4; ++r) {
                sv[r] += __shfl_xor(sv[r], m);
                dv[r] += __shfl_xor(dv[r], m);
            }
        }
        if (lc == 0) {
#pragma unroll
            for (int r = 0; r < 4; ++r) {
                int row = rowb + r;
                if (row < N) { as[row * 8 + c] = sv[r]; ad[row * 8 + c] = dv[r]; }
            }
        }
    }
}

// ---------------------------------------------------------------------------
// Phase A: bucket edges by dst>>8 into per-block slabs (localized scatter).
// ---------------------------------------------------------------------------
__global__ __launch_bounds__(512) void bucket_edges(const int* __restrict__ ei, int E,
                                                    uint2* __restrict__ slab,
                                                    int* __restrict__ cntG,
                                                    int* __restrict__ startG) {
    __shared__ int sS[ABLK];
    __shared__ int dS[ABLK];
    __shared__ int hist[512];
    __shared__ int cur[NBUCK];
    const int t = threadIdx.x;
    const int blk = blockIdx.x;
    const int base = blk * ABLK;
    int count = E - base; if (count > ABLK) count = ABLK;

    hist[t] = 0;
#pragma unroll
    for (int k = 0; k < EPT; ++k) {
        int i = k * 512 + t;
        int idx = base + i;
        if (i < count) { sS[i] = ei[idx]; dS[i] = ei[E + idx]; }
    }
    __syncthreads();
#pragma unroll
    for (int k = 0; k < EPT; ++k) {
        int i = k * 512 + t;
        if (i < count) atomicAdd(&hist[dS[i] >> 8], 1);
    }
    __syncthreads();
    int v = hist[t];
    for (int off = 1; off < 512; off <<= 1) {
        int u = t >= off ? hist[t - off] : 0;
        __syncthreads();
        hist[t] += u;
        __syncthreads();
    }
    int excl = hist[t] - v;
    if (t < NBUCK) {
        cntG[blk * NBUCK + t]   = v;
        startG[blk * NBUCK + t] = excl;
        cur[t] = excl;
    }
    __syncthreads();
#pragma unroll
    for (int k = 0; k < EPT; ++k) {
        int i = k * 512 + t;
        if (i < count) {
            int d = dS[i];
            int pos = atomicAdd(&cur[d >> 8], 1);
            slab[(size_t)blk * ABLK + pos] = make_uint2((unsigned)sS[i], (unsigned)d);
        }
    }
}

__global__ __launch_bounds__(64) void bucket_totals(const int* __restrict__ cntG, int nblk,
                                                    int* __restrict__ totalG) {
    int b = blockIdx.x;
    int lane = threadIdx.x;
    int s = 0;
    for (int blk = lane; blk < nblk; blk += 64) s += cntG[blk * NBUCK + b];
#pragma unroll
    for (int off = 32; off > 0; off >>= 1) s += __shfl_down(s, off);
    if (lane == 0) totalG[b] = s;
}

__global__ __launch_bounds__(512) void scan_buckets(const int* __restrict__ totalG,
                                                    int* __restrict__ bucketStart) {
    __shared__ int s[512];
    int t = threadIdx.x;
    int v = t < NBUCK ? totalG[t] : 0;
    s[t] = v;
    __syncthreads();
    for (int off = 1; off < 512; off <<= 1) {
        int u = t >= off ? s[t - off] : 0;
        __syncthreads();
        s[t] += u;
        __syncthreads();
    }
    int excl = s[t] - v;
    if (t <= NBUCK) bucketStart[t] = excl;
}

// ---------------------------------------------------------------------------
// Phase B: per bucket, PARALLEL gather (binary search over segment scan) into
// LDS, dst-histogram + scan -> rowptr; place sortedSrc in 16KB window.
// ---------------------------------------------------------------------------
__global__ __launch_bounds__(512) void build_csr(const uint2* __restrict__ slab,
                                                 const int* __restrict__ cntG,
                                                 const int* __restrict__ startG,
                                                 const int* __restrict__ bucketStart,
                                                 int nblk, int N, int E,
                                                 int* __restrict__ rowptr,
                                                 int* __restrict__ sortedSrc) {
    __shared__ uint2 eL[ABLK];
    __shared__ int incl[512];
    __shared__ int cS[512];
    __shared__ int stS[512];
    __shared__ int hist[512];
    __shared__ int lp[256];
    const int b = blockIdx.x;
    const int t = threadIdx.x;
    const int nodeBase = b << 8;

    int c = 0, st = 0;
    if (t < nblk) { c = cntG[t * NBUCK + b]; st = startG[t * NBUCK + b]; }
    cS[t] = c; stS[t] = st; hist[t] = 0; incl[t] = c;
    __syncthreads();
    for (int off = 1; off < 512; off <<= 1) {
        int u = t >= off ? incl[t - off] : 0;
        __syncthreads();
        incl[t] += u;
        __syncthreads();
    }
    const int total = incl[511];
    // parallel gather: for each output slot, binary-search its source segment
    for (int e = t; e < total; e += 512) {
        int lo = 0, hi = 511;
        while (lo < hi) { int mid = (lo + hi) >> 1; if (incl[mid] > e) hi = mid; else lo = mid + 1; }
        int loc = e - (incl[lo] - cS[lo]);
        eL[e] = slab[(size_t)lo * ABLK + stS[lo] + loc];
    }
    __syncthreads();
    for (int e = t; e < total; e += 512) atomicAdd(&hist[eL[e].y & 255], 1);
    __syncthreads();
    int hv = hist[t];
    for (int off = 1; off < 512; off <<= 1) {
        int u = t >= off ? hist[t - off] : 0;
        __syncthreads();
        hist[t] += u;
        __syncthreads();
    }
    int hexcl = hist[t] - hv;
    const int bs = bucketStart[b];
    int nodes = N - nodeBase; if (nodes > 256) nodes = 256;
    if (t < nodes) rowptr[nodeBase + t] = bs + hexcl;
    if (t < 256) lp[t] = hexcl;
    if (b == gridDim.x - 1 && t == 0) rowptr[N] = E;
    __syncthreads();
    for (int e = t; e < total; e += 512) {
        uint2 ed = eL[e];
        int pos = atomicAdd(&lp[ed.y & 255], 1);
        sortedSrc[bs + pos] = (int)ed.x;
    }
}

// ---------------------------------------------------------------------------
// Aggregate: one wave per dst node. Lane = (group g=lane>>4, p=lane&15).
// Lane p handles channels p*8..p*8+7 (head p>>1, bf16x8 = 16B load); the 4
// groups stride the edge list by 4. One exp chain per 4 edges per lane-slot.
// Butterfly xor16/32 combines groups; self-loop folded analytically.
// ---------------------------------------------------------------------------
__global__ __launch_bounds__(256) void aggregate(const int* __restrict__ rowptr,
                                                 const int* __restrict__ sortedSrc,
                                                 const short* __restrict__ h,
                                                 const float* __restrict__ as,
                                                 const float* __restrict__ ad,
                                                 const float* __restrict__ bias,
                                                 float* __restrict__ out, int N) {
    int node = blockIdx.x * 4 + (threadIdx.x >> 6);
    if (node >= N) return;
    int lane = threadIdx.x & 63;
    int g = lane >> 4, p = lane & 15, hh = p >> 1;
    int start = rowptr[node], end = rowptr[node + 1];
    float adv = ad[node * 8 + hh];

    float acc[8];
#pragma unroll
    for (int k = 0; k < 8; ++k) acc[k] = 0.f;
    float dsum = 0.f;

    int e = start + g;
    int j = (e < end) ? sortedSrc[e] : 0;
    while (e < end) {
        int jn = (e + 4 < end) ? sortedSrc[e + 4] : 0;   // prefetch next idx
        float t = as[j * 8 + hh] + adv;
        t = t > 0.f ? t : NEG_SLOPE * t;
        float w = __expf(t);
        uint4 hv = *(const uint4*)(h + (size_t)j * 128 + p * 8);
        acc[0] += w * bflo(hv.x); acc[1] += w * bfhi(hv.x);
        acc[2] += w * bflo(hv.y); acc[3] += w * bfhi(hv.y);
        acc[4] += w * bflo(hv.z); acc[5] += w * bfhi(hv.z);
        acc[6] += w * bflo(hv.w); acc[7] += w * bfhi(hv.w);
        dsum += w;
        j = jn; e += 4;
    }
    // combine the 4 edge groups
#pragma unroll
    for (int m = 16; m <= 32; m <<= 1) {
#pragma unroll
        for (int k = 0; k < 8; ++k) acc[k] += __shfl_xor(acc[k], m);
        dsum += __shfl_xor(dsum, m);
    }
    // self-loop
    {
        float t = as[node * 8 + hh] + adv;
        t = t > 0.f ? t : NEG_SLOPE * t;
        float w = __expf(t);
        uint4 hv = *(const uint4*)(h + (size_t)node * 128 + p * 8);
        acc[0] += w * bflo(hv.x); acc[1] += w * bfhi(hv.x);
        acc[2] += w * bflo(hv.y); acc[3] += w * bfhi(hv.y);
        acc[4] += w * bflo(hv.z); acc[5] += w * bfhi(hv.z);
        acc[6] += w * bflo(hv.w); acc[7] += w * bfhi(hv.w);
        dsum += w;
    }
    float inv = 1.0f / (dsum + 1e-16f);
    float4 b0 = *(const float4*)(bias + p * 8);
    float4 b1 = *(const float4*)(bias + p * 8 + 4);
    float o0 = acc[0] * inv + b0.x, o1 = acc[1] * inv + b0.y;
    float o2 = acc[2] * inv + b0.z, o3 = acc[3] * inv + b0.w;
    float o4 = acc[4] * inv + b1.x, o5 = acc[5] * inv + b1.y;
    float o6 = acc[6] * inv + b1.z, o7 = acc[7] * inv + b1.w;
    o0 = o0 > 0.f ? o0 : 0.f; o1 = o1 > 0.f ? o1 : 0.f;
    o2 = o2 > 0.f ? o2 : 0.f; o3 = o3 > 0.f ? o3 : 0.f;
    o4 = o4 > 0.f ? o4 : 0.f; o5 = o5 > 0.f ? o5 : 0.f;
    o6 = o6 > 0.f ? o6 : 0.f; o7 = o7 > 0.f ? o7 : 0.f;
    *(float4*)(out + (size_t)node * 128 + p * 8)     = make_float4(o0, o1, o2, o3);
    *(float4*)(out + (size_t)node * 128 + p * 8 + 4) = make_float4(o4, o5, o6, o7);
}

extern "C" void kernel_launch(void* const* d_in, const int* in_sizes, int n_in,
                              void* d_out, int out_size, void* d_ws, size_t ws_size,
                              hipStream_t stream) {
    const float* x     = (const float*)d_in[0];
    const int*   ei    = (const int*)d_in[1];
    const float* W     = (const float*)d_in[2];
    const float* a_src = (const float*)d_in[3];
    const float* a_dst = (const float*)d_in[4];
    const float* bias  = (const float*)d_in[5];
    float* out = (float*)d_out;

    const int N = in_sizes[0] / 128;   // 100000
    const int E = in_sizes[1] / 2;     // 1600000
    const int nblk = (E + ABLK - 1) / ABLK;  // 196

    char* ws = (char*)d_ws;
    size_t off = 0;
    auto alloc = [&](size_t bytes) { void* p = ws + off; off = (off + bytes + 255) & ~(size_t)255; return p; };
    short* h         = (short*)alloc((size_t)N * 128 * 2);
    float* as        = (float*)alloc((size_t)N * 8 * 4);
    float* ad        = (float*)alloc((size_t)N * 8 * 4);
    int*   sortedSrc = (int*)alloc((size_t)E * 4);
    int*   rowptr    = (int*)alloc((size_t)(N + 1) * 4);
    uint2* slab      = (uint2*)alloc((size_t)nblk * ABLK * 8);
    int*   cntG      = (int*)alloc((size_t)nblk * NBUCK * 4);
    int*   startG    = (int*)alloc((size_t)nblk * NBUCK * 4);
    int*   totalG    = (int*)alloc((size_t)NBUCK * 4);
    int*   bucketSt  = (int*)alloc((size_t)(NBUCK + 1) * 4);
    short* WtG       = (short*)alloc((size_t)128 * 128 * 2);

    // CSR build (no global atomics, localized scatters)
    bucket_edges<<<nblk, 512, 0, stream>>>(ei, E, slab, cntG, startG);
    bucket_totals<<<NBUCK, 64, 0, stream>>>(cntG, nblk, totalG);
    scan_buckets<<<1, 512, 0, stream>>>(totalG, bucketSt);
    build_csr<<<NBUCK, 512, 0, stream>>>(slab, cntG, startG, bucketSt, nblk, N, E, rowptr, sortedSrc);

    // Dense compute: MFMA GEMM with fused alpha epilogue
    prep_w<<<64, 256, 0, stream>>>(W, WtG);
    gemm_mfma<<<(N + 63) / 64, 256, 0, stream>>>(x, WtG, a_src, a_dst, h, as, ad, N);

    // Gather aggregation
    aggregate<<<(N + 3) / 4, 256, 0, stream>>>(rowptr, sortedSrc, h, as, ad, bias, out, N);
}

// Round 6
// 248.655 us; speedup vs baseline: 11.8394x; 1.0274x over previous
//
#include <hip/hip_runtime.h>
#include <hip/hip_bf16.h>

#define NEG_SLOPE 0.2f
#define NBUCK 782      // ceil(100000 / 128) buckets of 128 dst nodes
#define ABLK 8192      // edges per bucket_edges block
#define CAP 3072       // max edges per bucket (mean 2048, sd ~45 -> +22 sigma)

typedef __attribute__((ext_vector_type(8))) short bf16x8v;
typedef __attribute__((ext_vector_type(4))) float f32x4;

__device__ __forceinline__ unsigned f2bf_bits(float f) {
    unsigned u = __float_as_uint(f);
    return (u + 0x7fffu + ((u >> 16) & 1u)) >> 16;   // RNE fp32 -> bf16 bits
}
__device__ __forceinline__ float bflo(unsigned u) { return __uint_as_float(u << 16); }
__device__ __forceinline__ float bfhi(unsigned u) { return __uint_as_float(u & 0xffff0000u); }

// ---------------------------------------------------------------------------
// prep_w: W[128k][128n] fp32 -> WtG[n][k] bf16 bits (transposed, for B-frags)
// ---------------------------------------------------------------------------
__global__ __launch_bounds__(256) void prep_w(const float* __restrict__ W,
                                              short* __restrict__ WtG) {
    int id = blockIdx.x * 256 + threadIdx.x;   // 16384 total
    int n = id >> 7, k = id & 127;
    WtG[id] = (short)f2bf_bits(W[k * 128 + n]);
}

// ---------------------------------------------------------------------------
// MFMA GEMM: h[N,128] = bf16(x) @ bf16(W), fp32 acc, bf16 h out.
// Fused epilogue computes as/ad per (row, head) from the fp32 accumulator.
// ---------------------------------------------------------------------------
__global__ __launch_bounds__(256) void gemm_mfma(const float* __restrict__ x,
                                                 const short* __restrict__ WtG,
                                                 const float* __restrict__ a_src,
                                                 const float* __restrict__ a_dst,
                                                 short* __restrict__ hout,
                                                 float* __restrict__ as,
                                                 float* __restrict__ ad, int N) {
    __shared__ short xs[64 * 136];
    __shared__ short wt[128 * 136];
    const int tid = threadIdx.x;
    const int r0 = blockIdx.x * 64;

#pragma unroll
    for (int p = 0; p < 8; ++p) {
        int idx = p * 256 + tid;
        int n = idx >> 4, kk = (idx & 15) * 8;
        *(uint4*)&wt[n * 136 + kk] = *(const uint4*)(WtG + n * 128 + kk);
    }
#pragma unroll
    for (int p = 0; p < 8; ++p) {
        int lin = p * 1024 + tid * 4;
        int row = lin >> 7, k = lin & 127;
        int gr = r0 + row;
        int grc = gr < N ? gr : N - 1;
        float4 v = *(const float4*)(x + (size_t)grc * 128 + k);
        unsigned p0 = f2bf_bits(v.x) | (f2bf_bits(v.y) << 16);
        unsigned p1 = f2bf_bits(v.z) | (f2bf_bits(v.w) << 16);
        *(uint2*)&xs[row * 136 + k] = make_uint2(p0, p1);
    }
    __syncthreads();

    const int wv = tid >> 6;
    const int lane = tid & 63;
    const int lc = lane & 15, quad = lane >> 4;
    f32x4 acc[8];
#pragma unroll
    for (int c = 0; c < 8; ++c) acc[c] = (f32x4){0.f, 0.f, 0.f, 0.f};
    const short* aB = &xs[(wv * 16 + lc) * 136 + quad * 8];
    const short* bB = &wt[lc * 136 + quad * 8];
#pragma unroll
    for (int kc = 0; kc < 4; ++kc) {
        bf16x8v af = *(const bf16x8v*)(aB + kc * 32);
#pragma unroll
        for (int c = 0; c < 8; ++c) {
            bf16x8v bf = *(const bf16x8v*)(bB + c * (16 * 136) + kc * 32);
            acc[c] = __builtin_amdgcn_mfma_f32_16x16x32_bf16(af, bf, acc[c], 0, 0, 0);
        }
    }

    const int rowb = r0 + wv * 16 + quad * 4;
#pragma unroll
    for (int c = 0; c < 8; ++c) {
        float asc = a_src[c * 16 + lc];
        float adc = a_dst[c * 16 + lc];
        float sv[4], dv[4];
#pragma unroll
        for (int r = 0; r < 4; ++r) {
            float hv = acc[c][r];
            int row = rowb + r;
            if (row < N) hout[(size_t)row * 128 + c * 16 + lc] = (short)f2bf_bits(hv);
            sv[r] = hv * asc;
            dv[r] = hv * adc;
        }
#pragma unroll
        for (int m = 1; m <= 8; m <<= 1) {
#pragma unroll
            for (int r = 0; r < 4; ++r) {
                sv[r] += __shfl_xor(sv[r], m);
                dv[r] += __shfl_xor(dv[r], m);
            }
        }
        if (lc == 0) {
#pragma unroll
            for (int r = 0; r < 4; ++r) {
                int row = rowb + r;
                if (row < N) { as[row * 8 + c] = sv[r]; ad[row * 8 + c] = dv[r]; }
            }
        }
    }
}

// ---------------------------------------------------------------------------
// Phase A: bucket edges by dst>>7 into per-block slabs. Edges staged in
// REGISTERS (8/thread, 1024 threads); packed uint32 = src | (dst&127)<<17.
// ---------------------------------------------------------------------------
__global__ __launch_bounds__(1024) void bucket_edges(const int* __restrict__ ei, int E,
                                                     unsigned* __restrict__ slab,
                                                     int* __restrict__ cntG,
                                                     int* __restrict__ startG) {
    __shared__ int hist[1024];
    __shared__ int cur[NBUCK];
    const int t = threadIdx.x;
    const int blk = blockIdx.x;
    const int base = blk * ABLK;
    int count = E - base; if (count > ABLK) count = ABLK;

    int sr[8], dr[8];
    hist[t] = 0;
#pragma unroll
    for (int k = 0; k < 8; ++k) {
        int i = k * 1024 + t;
        if (i < count) { sr[k] = ei[base + i]; dr[k] = ei[E + base + i]; }
    }
    __syncthreads();
#pragma unroll
    for (int k = 0; k < 8; ++k) {
        int i = k * 1024 + t;
        if (i < count) atomicAdd(&hist[dr[k] >> 7], 1);
    }
    __syncthreads();
    int v = hist[t];
    for (int off = 1; off < 1024; off <<= 1) {
        int u = t >= off ? hist[t - off] : 0;
        __syncthreads();
        hist[t] += u;
        __syncthreads();
    }
    int excl = hist[t] - v;
    if (t < NBUCK) {
        cntG[blk * NBUCK + t]   = v;
        startG[blk * NBUCK + t] = excl;
        cur[t] = excl;
    }
    __syncthreads();
#pragma unroll
    for (int k = 0; k < 8; ++k) {
        int i = k * 1024 + t;
        if (i < count) {
            int d = dr[k];
            int pos = atomicAdd(&cur[d >> 7], 1);
            slab[(size_t)blk * ABLK + pos] = (unsigned)sr[k] | ((unsigned)(d & 127) << 17);
        }
    }
}

// ---------------------------------------------------------------------------
// Phase B (fused sort+aggregate): per bucket of 128 dst nodes.
// 1) gather bucket's packed edges from slabs into LDS (binary search)
// 2) LDS hist+scan+place -> per-node edge lists in LDS
// 3) aggregation: 8 waves x 16 nodes; lane = (group g=lane>>4 strides edges
//    by 4, p=lane&15 handles channels p*8..p*8+7, head p>>1); butterfly
//    xor16/32 combines groups; self-loop analytic; write out once.
// ---------------------------------------------------------------------------
__global__ __launch_bounds__(512) void bucket_aggregate(const unsigned* __restrict__ slab,
                                                        const int* __restrict__ cntG,
                                                        const int* __restrict__ startG,
                                                        int nblk, int N,
                                                        const short* __restrict__ h,
                                                        const float* __restrict__ as,
                                                        const float* __restrict__ ad,
                                                        const float* __restrict__ bias,
                                                        float* __restrict__ out) {
    __shared__ int eL[CAP];
    __shared__ int sortedL[CAP];
    __shared__ int incl[512];
    __shared__ int cS[512];
    __shared__ int stS[512];
    __shared__ int rs[128];
    __shared__ int lp[128];
    const int bb = blockIdx.x;
    const int t = threadIdx.x;
    const int nodeBase = bb << 7;

    int c = 0, st = 0;
    if (t < nblk) { c = cntG[t * NBUCK + bb]; st = startG[t * NBUCK + bb]; }
    cS[t] = c; stS[t] = st; incl[t] = c;
    if (t < 128) lp[t] = 0;
    __syncthreads();
    for (int off = 1; off < 512; off <<= 1) {
        int u = t >= off ? incl[t - off] : 0;
        __syncthreads();
        incl[t] += u;
        __syncthreads();
    }
    const int total = incl[511];
    // parallel gather from slabs
    for (int e = t; e < total; e += 512) {
        int lo = 0, hi = nblk - 1;
        while (lo < hi) { int mid = (lo + hi) >> 1; if (incl[mid] > e) hi = mid; else lo = mid + 1; }
        int loc = e - (incl[lo] - cS[lo]);
        eL[e] = (int)slab[(size_t)lo * ABLK + stS[lo] + loc];
    }
    __syncthreads();
    // histogram by local dst
    for (int e = t; e < total; e += 512) atomicAdd(&lp[((unsigned)eL[e]) >> 17], 1);
    __syncthreads();
    // scan 128 (exclusive)
    int hv = (t < 128) ? lp[t] : 0;
    for (int off = 1; off < 128; off <<= 1) {
        int u = (t >= off && t < 128) ? lp[t - off] : 0;
        __syncthreads();
        if (t < 128) lp[t] += u;
        __syncthreads();
    }
    if (t < 128) {
        int ex = lp[t] - hv;
        rs[t] = ex;
        lp[t] = ex;     // placement cursor
    }
    __syncthreads();
    // place into per-node lists
    for (int e = t; e < total; e += 512) {
        unsigned pk = (unsigned)eL[e];
        int pos = atomicAdd(&lp[pk >> 17], 1);
        sortedL[pos] = (int)(pk & 0x1FFFFu);
    }
    __syncthreads();
    // ---- aggregation ----
    const int wv = t >> 6;
    const int lane = t & 63;
    const int g = lane >> 4, p = lane & 15, hh = p >> 1;
    float4 b0 = *(const float4*)(bias + p * 8);
    float4 b1 = *(const float4*)(bias + p * 8 + 4);
    for (int nl = wv * 16; nl < wv * 16 + 16; ++nl) {
        int gn = nodeBase + nl;
        if (gn >= N) break;
        int s0 = rs[nl], e0 = lp[nl];     // lp[nl] is now row end
        float adv = ad[gn * 8 + hh];

        float acc[8];
#pragma unroll
        for (int k = 0; k < 8; ++k) acc[k] = 0.f;
        float dsum = 0.f;

        int e = s0 + g;
        int j = (e < e0) ? sortedL[e] : 0;
        while (e < e0) {
            int jn = (e + 4 < e0) ? sortedL[e + 4] : 0;
            float tt = as[j * 8 + hh] + adv;
            tt = tt > 0.f ? tt : NEG_SLOPE * tt;
            float w = __expf(tt);
            uint4 hr = *(const uint4*)(h + (size_t)j * 128 + p * 8);
            acc[0] += w * bflo(hr.x); acc[1] += w * bfhi(hr.x);
            acc[2] += w * bflo(hr.y); acc[3] += w * bfhi(hr.y);
            acc[4] += w * bflo(hr.z); acc[5] += w * bfhi(hr.z);
            acc[6] += w * bflo(hr.w); acc[7] += w * bfhi(hr.w);
            dsum += w;
            j = jn; e += 4;
        }
#pragma unroll
        for (int m = 16; m <= 32; m <<= 1) {
#pragma unroll
            for (int k = 0; k < 8; ++k) acc[k] += __shfl_xor(acc[k], m);
            dsum += __shfl_xor(dsum, m);
        }
        // self-loop
        {
            float tt = as[gn * 8 + hh] + adv;
            tt = tt > 0.f ? tt : NEG_SLOPE * tt;
            float w = __expf(tt);
            uint4 hr = *(const uint4*)(h + (size_t)gn * 128 + p * 8);
            acc[0] += w * bflo(hr.x); acc[1] += w * bfhi(hr.x);
            acc[2] += w * bflo(hr.y); acc[3] += w * bfhi(hr.y);
            acc[4] += w * bflo(hr.z); acc[5] += w * bfhi(hr.z);
            acc[6] += w * bflo(hr.w); acc[7] += w * bfhi(hr.w);
            dsum += w;
        }
        float inv = 1.0f / (dsum + 1e-16f);
        float o0 = acc[0] * inv + b0.x, o1 = acc[1] * inv + b0.y;
        float o2 = acc[2] * inv + b0.z, o3 = acc[3] * inv + b0.w;
        float o4 = acc[4] * inv + b1.x, o5 = acc[5] * inv + b1.y;
        float o6 = acc[6] * inv + b1.z, o7 = acc[7] * inv + b1.w;
        o0 = o0 > 0.f ? o0 : 0.f; o1 = o1 > 0.f ? o1 : 0.f;
        o2 = o2 > 0.f ? o2 : 0.f; o3 = o3 > 0.f ? o3 : 0.f;
        o4 = o4 > 0.f ? o4 : 0.f; o5 = o5 > 0.f ? o5 : 0.f;
        o6 = o6 > 0.f ? o6 : 0.f; o7 = o7 > 0.f ? o7 : 0.f;
        *(float4*)(out + (size_t)gn * 128 + p * 8)     = make_float4(o0, o1, o2, o3);
        *(float4*)(out + (size_t)gn * 128 + p * 8 + 4) = make_float4(o4, o5, o6, o7);
    }
}

extern "C" void kernel_launch(void* const* d_in, const int* in_sizes, int n_in,
                              void* d_out, int out_size, void* d_ws, size_t ws_size,
                              hipStream_t stream) {
    const float* x     = (const float*)d_in[0];
    const int*   ei    = (const int*)d_in[1];
    const float* W     = (const float*)d_in[2];
    const float* a_src = (const float*)d_in[3];
    const float* a_dst = (const float*)d_in[4];
    const float* bias  = (const float*)d_in[5];
    float* out = (float*)d_out;

    const int N = in_sizes[0] / 128;   // 100000
    const int E = in_sizes[1] / 2;     // 1600000
    const int nblk = (E + ABLK - 1) / ABLK;  // 196

    char* ws = (char*)d_ws;
    size_t off = 0;
    auto alloc = [&](size_t bytes) { void* p = ws + off; off = (off + bytes + 255) & ~(size_t)255; return p; };
    short*    h      = (short*)alloc((size_t)N * 128 * 2);
    float*    as     = (float*)alloc((size_t)N * 8 * 4);
    float*    ad     = (float*)alloc((size_t)N * 8 * 4);
    unsigned* slab   = (unsigned*)alloc((size_t)nblk * ABLK * 4);
    int*      cntG   = (int*)alloc((size_t)nblk * NBUCK * 4);
    int*      startG = (int*)alloc((size_t)nblk * NBUCK * 4);
    short*    WtG    = (short*)alloc((size_t)128 * 128 * 2);

    prep_w<<<64, 256, 0, stream>>>(W, WtG);
    gemm_mfma<<<(N + 63) / 64, 256, 0, stream>>>(x, WtG, a_src, a_dst, h, as, ad, N);
    bucket_edges<<<nblk, 1024, 0, stream>>>(ei, E, slab, cntG, startG);
    bucket_aggregate<<<NBUCK, 512, 0, stream>>>(slab, cntG, startG, nblk, N,
                                                h, as, ad, bias, out);
}

// Round 7
// 246.510 us; speedup vs baseline: 11.9424x; 1.0087x over previous
//
#include <hip/hip_runtime.h>
#include <hip/hip_bf16.h>

#define NEG_SLOPE 0.2f
#define NBUCK 782      // ceil(100000 / 128) buckets of 128 dst nodes
#define ABLK 8192      // edges per bucket_edges block
#define CAP 3072       // max edges per bucket (mean 2048, sd ~45 -> +22 sigma)

typedef __attribute__((ext_vector_type(8))) short bf16x8v;
typedef __attribute__((ext_vector_type(4))) float f32x4;

__device__ __forceinline__ unsigned f2bf_bits(float f) {
    unsigned u = __float_as_uint(f);
    return (u + 0x7fffu + ((u >> 16) & 1u)) >> 16;   // RNE fp32 -> bf16 bits
}
__device__ __forceinline__ float bflo(unsigned u) { return __uint_as_float(u << 16); }
__device__ __forceinline__ float bfhi(unsigned u) { return __uint_as_float(u & 0xffff0000u); }

// ---------------------------------------------------------------------------
// prep_w: W[128k][128n] fp32 -> WtG[n][k] bf16 bits (transposed, for B-frags)
// ---------------------------------------------------------------------------
__global__ __launch_bounds__(256) void prep_w(const float* __restrict__ W,
                                              short* __restrict__ WtG) {
    int id = blockIdx.x * 256 + threadIdx.x;   // 16384 total
    int n = id >> 7, k = id & 127;
    WtG[id] = (short)f2bf_bits(W[k * 128 + n]);
}

// ---------------------------------------------------------------------------
// MFMA GEMM: h[N,128] = bf16(x) @ bf16(W), fp32 acc, bf16 h out.
// Fused epilogue computes as/ad per (row, head) from the fp32 accumulator.
// ---------------------------------------------------------------------------
__global__ __launch_bounds__(256) void gemm_mfma(const float* __restrict__ x,
                                                 const short* __restrict__ WtG,
                                                 const float* __restrict__ a_src,
                                                 const float* __restrict__ a_dst,
                                                 short* __restrict__ hout,
                                                 float* __restrict__ as,
                                                 float* __restrict__ ad, int N) {
    __shared__ short xs[64 * 136];
    __shared__ short wt[128 * 136];
    const int tid = threadIdx.x;
    const int r0 = blockIdx.x * 64;

#pragma unroll
    for (int p = 0; p < 8; ++p) {
        int idx = p * 256 + tid;
        int n = idx >> 4, kk = (idx & 15) * 8;
        *(uint4*)&wt[n * 136 + kk] = *(const uint4*)(WtG + n * 128 + kk);
    }
#pragma unroll
    for (int p = 0; p < 8; ++p) {
        int lin = p * 1024 + tid * 4;
        int row = lin >> 7, k = lin & 127;
        int gr = r0 + row;
        int grc = gr < N ? gr : N - 1;
        float4 v = *(const float4*)(x + (size_t)grc * 128 + k);
        unsigned p0 = f2bf_bits(v.x) | (f2bf_bits(v.y) << 16);
        unsigned p1 = f2bf_bits(v.z) | (f2bf_bits(v.w) << 16);
        *(uint2*)&xs[row * 136 + k] = make_uint2(p0, p1);
    }
    __syncthreads();

    const int wv = tid >> 6;
    const int lane = tid & 63;
    const int lc = lane & 15, quad = lane >> 4;
    f32x4 acc[8];
#pragma unroll
    for (int c = 0; c < 8; ++c) acc[c] = (f32x4){0.f, 0.f, 0.f, 0.f};
    const short* aB = &xs[(wv * 16 + lc) * 136 + quad * 8];
    const short* bB = &wt[lc * 136 + quad * 8];
#pragma unroll
    for (int kc = 0; kc < 4; ++kc) {
        bf16x8v af = *(const bf16x8v*)(aB + kc * 32);
#pragma unroll
        for (int c = 0; c < 8; ++c) {
            bf16x8v bf = *(const bf16x8v*)(bB + c * (16 * 136) + kc * 32);
            acc[c] = __builtin_amdgcn_mfma_f32_16x16x32_bf16(af, bf, acc[c], 0, 0, 0);
        }
    }

    const int rowb = r0 + wv * 16 + quad * 4;
#pragma unroll
    for (int c = 0; c < 8; ++c) {
        float asc = a_src[c * 16 + lc];
        float adc = a_dst[c * 16 + lc];
        float sv[4], dv[4];
#pragma unroll
        for (int r = 0; r < 4; ++r) {
            float hv = acc[c][r];
            int row = rowb + r;
            if (row < N) hout[(size_t)row * 128 + c * 16 + lc] = (short)f2bf_bits(hv);
            sv[r] = hv * asc;
            dv[r] = hv * adc;
        }
#pragma unroll
        for (int m = 1; m <= 8; m <<= 1) {
#pragma unroll
            for (int r = 0; r < 4; ++r) {
                sv[r] += __shfl_xor(sv[r], m);
                dv[r] += __shfl_xor(dv[r], m);
            }
        }
        if (lc == 0) {
#pragma unroll
            for (int r = 0; r < 4; ++r) {
                int row = rowb + r;
                if (row < N) { as[row * 8 + c] = sv[r]; ad[row * 8 + c] = dv[r]; }
            }
        }
    }
}

// ---------------------------------------------------------------------------
// Phase A: bucket edges by dst>>7 into per-block slabs. Register staging,
// packed uint32 = src | (dst&127)<<17. Hierarchical shfl scan (3 barriers).
// ---------------------------------------------------------------------------
__global__ __launch_bounds__(1024) void bucket_edges(const int* __restrict__ ei, int E,
                                                     unsigned* __restrict__ slab,
                                                     int* __restrict__ cntG,
                                                     int* __restrict__ startG) {
    __shared__ int hist[1024];
    __shared__ int cur[NBUCK];
    __shared__ int wpart[16];
    const int t = threadIdx.x;
    const int blk = blockIdx.x;
    const int base = blk * ABLK;
    int count = E - base; if (count > ABLK) count = ABLK;

    int sr[8], dr[8];
    hist[t] = 0;
#pragma unroll
    for (int k = 0; k < 8; ++k) {
        int i = k * 1024 + t;
        if (i < count) { sr[k] = ei[base + i]; dr[k] = ei[E + base + i]; }
    }
    __syncthreads();
#pragma unroll
    for (int k = 0; k < 8; ++k) {
        int i = k * 1024 + t;
        if (i < count) atomicAdd(&hist[dr[k] >> 7], 1);
    }
    __syncthreads();
    int v = hist[t];
    int lane = t & 63, wid = t >> 6;
    int sc = v;
#pragma unroll
    for (int off = 1; off < 64; off <<= 1) { int u = __shfl_up(sc, off); if (lane >= off) sc += u; }
    if (lane == 63) wpart[wid] = sc;
    __syncthreads();
    if (wid == 0 && lane < 16) {
        int wv = wpart[lane], wsum = wv;
#pragma unroll
        for (int off = 1; off < 16; off <<= 1) { int u = __shfl_up(wsum, off); if (lane >= off) wsum += u; }
        wpart[lane] = wsum - wv;
    }
    __syncthreads();
    int excl = sc - v + wpart[wid];
    if (t < NBUCK) {
        cntG[blk * NBUCK + t]   = v;
        startG[blk * NBUCK + t] = excl;
        cur[t] = excl;
    }
    __syncthreads();
#pragma unroll
    for (int k = 0; k < 8; ++k) {
        int i = k * 1024 + t;
        if (i < count) {
            int d = dr[k];
            int pos = atomicAdd(&cur[d >> 7], 1);
            slab[(size_t)blk * ABLK + pos] = (unsigned)sr[k] | ((unsigned)(d & 127) << 17);
        }
    }
}

// ---------------------------------------------------------------------------
// Phase B: per bucket of 128 dst nodes, gather packed edges into LDS (binary
// search over segment scan), hist + scan -> rowS/rowE (fixed CAP region per
// bucket, so NO global scan pass), place sortedSrc in the bucket's window.
// ---------------------------------------------------------------------------
__global__ __launch_bounds__(512) void build_csr(const unsigned* __restrict__ slab,
                                                 const int* __restrict__ cntG,
                                                 const int* __restrict__ startG,
                                                 int nblk, int N,
                                                 int* __restrict__ rowS,
                                                 int* __restrict__ rowE,
                                                 int* __restrict__ sortedSrc) {
    __shared__ int eL[CAP];
    __shared__ int incl[512];
    __shared__ int cS[512];
    __shared__ int stS[512];
    __shared__ int lp[128];
    __shared__ int wpart[8];
    __shared__ int halfSum;
    const int bb = blockIdx.x;
    const int t = threadIdx.x;
    const int nodeBase = bb << 7;
    const int bBase = bb * CAP;

    int c = 0, st = 0;
    if (t < nblk) { c = cntG[t * NBUCK + bb]; st = startG[t * NBUCK + bb]; }
    cS[t] = c; stS[t] = st;
    if (t < 128) lp[t] = 0;
    int lane = t & 63, wid = t >> 6;
    int sc = c;
#pragma unroll
    for (int off = 1; off < 64; off <<= 1) { int u = __shfl_up(sc, off); if (lane >= off) sc += u; }
    if (lane == 63) wpart[wid] = sc;
    __syncthreads();
    if (wid == 0 && lane < 8) {
        int wv = wpart[lane], wsum = wv;
#pragma unroll
        for (int off = 1; off < 8; off <<= 1) { int u = __shfl_up(wsum, off); if (lane >= off) wsum += u; }
        wpart[lane] = wsum - wv;
    }
    __syncthreads();
    incl[t] = sc + wpart[wid];
    __syncthreads();
    int total = incl[511];
    if (total > CAP) total = CAP;   // statically impossible; guards LDS OOB
    // parallel gather from slabs
    for (int e = t; e < total; e += 512) {
        int lo = 0, hi = nblk - 1;
        while (lo < hi) { int mid = (lo + hi) >> 1; if (incl[mid] > e) hi = mid; else lo = mid + 1; }
        int loc = e - (incl[lo] - cS[lo]);
        eL[e] = (int)slab[(size_t)lo * ABLK + stS[lo] + loc];
    }
    __syncthreads();
    for (int e = t; e < total; e += 512) atomicAdd(&lp[((unsigned)eL[e]) >> 17], 1);
    __syncthreads();
    // scan 128 node counts (waves 0,1)
    int cnt = 0, s2 = 0;
    if (t < 128) {
        cnt = lp[t];
        s2 = cnt;
#pragma unroll
        for (int off = 1; off < 64; off <<= 1) { int u = __shfl_up(s2, off); if (lane >= off) s2 += u; }
        if (t == 63) halfSum = s2;
    }
    __syncthreads();
    if (t < 128) {
        int inc2 = s2 + (t >= 64 ? halfSum : 0);
        int ex = inc2 - cnt;
        int gn = nodeBase + t;
        if (gn < N) { rowS[gn] = bBase + ex; rowE[gn] = bBase + ex + cnt; }
        lp[t] = ex;
    }
    __syncthreads();
    // place into the bucket's fixed window
    for (int e = t; e < total; e += 512) {
        unsigned pk = (unsigned)eL[e];
        int pos = atomicAdd(&lp[pk >> 17], 1);
        sortedSrc[bBase + pos] = (int)(pk & 0x1FFFFu);
    }
}

// ---------------------------------------------------------------------------
// Aggregate: one wave per dst node. Lane = (group g=lane>>4 strides edges by
// 4, p=lane&15 handles channels p*8..p*8+7, head p>>1). Software-pipelined:
// j, as[j], and the h row are prefetched one iteration ahead (2x MLP).
// Butterfly xor16/32 combines groups; self-loop analytic.
// ---------------------------------------------------------------------------
__global__ __launch_bounds__(256) void aggregate(const int* __restrict__ rowS,
                                                 const int* __restrict__ rowE,
                                                 const int* __restrict__ sortedSrc,
                                                 const short* __restrict__ h,
                                                 const float* __restrict__ as,
                                                 const float* __restrict__ ad,
                                                 const float* __restrict__ bias,
                                                 float* __restrict__ out, int N) {
    int node = blockIdx.x * 4 + (threadIdx.x >> 6);
    if (node >= N) return;
    int lane = threadIdx.x & 63;
    int g = lane >> 4, p = lane & 15, hh = p >> 1;
    int start = rowS[node], end = rowE[node];
    float adv = ad[node * 8 + hh];

    float acc[8];
#pragma unroll
    for (int k = 0; k < 8; ++k) acc[k] = 0.f;
    float dsum = 0.f;

    int e = start + g;
    float asv = 0.f; uint4 hr;
    if (e < end) {
        int j = sortedSrc[e];
        asv = as[j * 8 + hh];
        hr = *(const uint4*)(h + (size_t)j * 128 + p * 8);
    }
    while (e < end) {
        int en = e + 4;
        float asn = 0.f; uint4 hn;
        if (en < end) {
            int jn = sortedSrc[en];
            asn = as[jn * 8 + hh];
            hn = *(const uint4*)(h + (size_t)jn * 128 + p * 8);
        }
        float tt = asv + adv;
        tt = tt > 0.f ? tt : NEG_SLOPE * tt;
        float w = __expf(tt);
        acc[0] += w * bflo(hr.x); acc[1] += w * bfhi(hr.x);
        acc[2] += w * bflo(hr.y); acc[3] += w * bfhi(hr.y);
        acc[4] += w * bflo(hr.z); acc[5] += w * bfhi(hr.z);
        acc[6] += w * bflo(hr.w); acc[7] += w * bfhi(hr.w);
        dsum += w;
        asv = asn; hr = hn; e = en;
    }
#pragma unroll
    for (int m = 16; m <= 32; m <<= 1) {
#pragma unroll
        for (int k = 0; k < 8; ++k) acc[k] += __shfl_xor(acc[k], m);
        dsum += __shfl_xor(dsum, m);
    }
    // self-loop
    {
        float tt = as[node * 8 + hh] + adv;
        tt = tt > 0.f ? tt : NEG_SLOPE * tt;
        float w = __expf(tt);
        uint4 hv = *(const uint4*)(h + (size_t)node * 128 + p * 8);
        acc[0] += w * bflo(hv.x); acc[1] += w * bfhi(hv.x);
        acc[2] += w * bflo(hv.y); acc[3] += w * bfhi(hv.y);
        acc[4] += w * bflo(hv.z); acc[5] += w * bfhi(hv.z);
        acc[6] += w * bflo(hv.w); acc[7] += w * bfhi(hv.w);
        dsum += w;
    }
    float inv = 1.0f / (dsum + 1e-16f);
    float4 b0 = *(const float4*)(bias + p * 8);
    float4 b1 = *(const float4*)(bias + p * 8 + 4);
    float o0 = acc[0] * inv + b0.x, o1 = acc[1] * inv + b0.y;
    float o2 = acc[2] * inv + b0.z, o3 = acc[3] * inv + b0.w;
    float o4 = acc[4] * inv + b1.x, o5 = acc[5] * inv + b1.y;
    float o6 = acc[6] * inv + b1.z, o7 = acc[7] * inv + b1.w;
    o0 = o0 > 0.f ? o0 : 0.f; o1 = o1 > 0.f ? o1 : 0.f;
    o2 = o2 > 0.f ? o2 : 0.f; o3 = o3 > 0.f ? o3 : 0.f;
    o4 = o4 > 0.f ? o4 : 0.f; o5 = o5 > 0.f ? o5 : 0.f;
    o6 = o6 > 0.f ? o6 : 0.f; o7 = o7 > 0.f ? o7 : 0.f;
    *(float4*)(out + (size_t)node * 128 + p * 8)     = make_float4(o0, o1, o2, o3);
    *(float4*)(out + (size_t)node * 128 + p * 8 + 4) = make_float4(o4, o5, o6, o7);
}

extern "C" void kernel_launch(void* const* d_in, const int* in_sizes, int n_in,
                              void* d_out, int out_size, void* d_ws, size_t ws_size,
                              hipStream_t stream) {
    const float* x     = (const float*)d_in[0];
    const int*   ei    = (const int*)d_in[1];
    const float* W     = (const float*)d_in[2];
    const float* a_src = (const float*)d_in[3];
    const float* a_dst = (const float*)d_in[4];
    const float* bias  = (const float*)d_in[5];
    float* out = (float*)d_out;

    const int N = in_sizes[0] / 128;   // 100000
    const int E = in_sizes[1] / 2;     // 1600000
    const int nblk = (E + ABLK - 1) / ABLK;  // 196

    char* ws = (char*)d_ws;
    size_t off = 0;
    auto alloc = [&](size_t bytes) { void* p = ws + off; off = (off + bytes + 255) & ~(size_t)255; return p; };
    short*    h         = (short*)alloc((size_t)N * 128 * 2);
    float*    as        = (float*)alloc((size_t)N * 8 * 4);
    float*    ad        = (float*)alloc((size_t)N * 8 * 4);
    unsigned* slab      = (unsigned*)alloc((size_t)nblk * ABLK * 4);
    int*      cntG      = (int*)alloc((size_t)nblk * NBUCK * 4);
    int*      startG    = (int*)alloc((size_t)nblk * NBUCK * 4);
    int*      sortedSrc = (int*)alloc((size_t)NBUCK * CAP * 4);
    int*      rowS      = (int*)alloc((size_t)N * 4);
    int*      rowE      = (int*)alloc((size_t)N * 4);
    short*    WtG       = (short*)alloc((size_t)128 * 128 * 2);

    prep_w<<<64, 256, 0, stream>>>(W, WtG);
    gemm_mfma<<<(N + 63) / 64, 256, 0, stream>>>(x, WtG, a_src, a_dst, h, as, ad, N);
    bucket_edges<<<nblk, 1024, 0, stream>>>(ei, E, slab, cntG, startG);
    build_csr<<<NBUCK, 512, 0, stream>>>(slab, cntG, startG, nblk, N, rowS, rowE, sortedSrc);
    aggregate<<<(N + 3) / 4, 256, 0, stream>>>(rowS, rowE, sortedSrc, h, as, ad, bias, out, N);
}

// Round 8
// 234.966 us; speedup vs baseline: 12.5292x; 1.0491x over previous
//
#include <hip/hip_runtime.h>
#include <hip/hip_bf16.h>

#define NEG_SLOPE 0.2f
#define NBUCK 782      // ceil(100000 / 128) buckets of 128 dst nodes
#define ABLK 8192      // edges per bucket_edges block
#define CAP 3072       // max edges per bucket (mean 2048, sd ~45 -> +22 sigma)

typedef __attribute__((ext_vector_type(8))) short bf16x8v;
typedef __attribute__((ext_vector_type(4))) float f32x4;

__device__ __forceinline__ unsigned f2bf_bits(float f) {
    unsigned u = __float_as_uint(f);
    return (u + 0x7fffu + ((u >> 16) & 1u)) >> 16;   // RNE fp32 -> bf16 bits
}
__device__ __forceinline__ float bflo(unsigned u) { return __uint_as_float(u << 16); }
__device__ __forceinline__ float bfhi(unsigned u) { return __uint_as_float(u & 0xffff0000u); }

// ---------------------------------------------------------------------------
// prep_w: build extended B^T [144][128] bf16:
//   rows 0..127:  Wt[n][k] = W[k][n]
//   rows 128..135: Wa[h][k] = sum_d W[k][h*16+d] * a_src[h][d]   (as columns)
//   rows 136..143: Wb[h][k] = sum_d W[k][h*16+d] * a_dst[h][d]   (ad columns)
// ---------------------------------------------------------------------------
__global__ __launch_bounds__(256) void prep_w(const float* __restrict__ W,
                                              const float* __restrict__ a_src,
                                              const float* __restrict__ a_dst,
                                              short* __restrict__ WtE) {
    int id = blockIdx.x * 256 + threadIdx.x;   // 144*128 = 18432
    if (id >= 144 * 128) return;
    int n = id >> 7, k = id & 127;
    float v;
    if (n < 128) {
        v = W[k * 128 + n];
    } else if (n < 136) {
        int hh = n - 128; float s = 0.f;
#pragma unroll
        for (int d = 0; d < 16; ++d) s += W[k * 128 + hh * 16 + d] * a_src[hh * 16 + d];
        v = s;
    } else {
        int hh = n - 136; float s = 0.f;
#pragma unroll
        for (int d = 0; d < 16; ++d) s += W[k * 128 + hh * 16 + d] * a_dst[hh * 16 + d];
        v = s;
    }
    WtE[id] = (short)f2bf_bits(v);
}

// ---------------------------------------------------------------------------
// MFMA GEMM: [h | as | ad] = bf16(x) @ B[128,144], fp32 acc.
// Block: 256 thr = 4 waves, 64 rows. Wave: 16 rows x 144 cols = 9 MFMA tiles.
// Epilogue is pure stores (alpha columns replace the old shuffle reduction).
// ---------------------------------------------------------------------------
__global__ __launch_bounds__(256) void gemm_mfma(const float* __restrict__ x,
                                                 const short* __restrict__ WtE,
                                                 short* __restrict__ hout,
                                                 float* __restrict__ as,
                                                 float* __restrict__ ad, int N) {
    __shared__ short xs[64 * 136];
    __shared__ short wt[144 * 136];
    const int tid = threadIdx.x;
    const int r0 = blockIdx.x * 64;

#pragma unroll
    for (int p = 0; p < 9; ++p) {
        int idx = p * 256 + tid;           // 2304 chunks of 8 shorts
        int n = idx >> 4, kk = (idx & 15) * 8;
        *(uint4*)&wt[n * 136 + kk] = *(const uint4*)(WtE + n * 128 + kk);
    }
#pragma unroll
    for (int p = 0; p < 8; ++p) {
        int lin = p * 1024 + tid * 4;
        int row = lin >> 7, k = lin & 127;
        int gr = r0 + row;
        int grc = gr < N ? gr : N - 1;
        float4 v = *(const float4*)(x + (size_t)grc * 128 + k);
        unsigned p0 = f2bf_bits(v.x) | (f2bf_bits(v.y) << 16);
        unsigned p1 = f2bf_bits(v.z) | (f2bf_bits(v.w) << 16);
        *(uint2*)&xs[row * 136 + k] = make_uint2(p0, p1);
    }
    __syncthreads();

    const int wv = tid >> 6;
    const int lane = tid & 63;
    const int lc = lane & 15, quad = lane >> 4;
    f32x4 acc[9];
#pragma unroll
    for (int c = 0; c < 9; ++c) acc[c] = (f32x4){0.f, 0.f, 0.f, 0.f};
    const short* aB = &xs[(wv * 16 + lc) * 136 + quad * 8];
    const short* bB = &wt[lc * 136 + quad * 8];
#pragma unroll
    for (int kc = 0; kc < 4; ++kc) {
        bf16x8v af = *(const bf16x8v*)(aB + kc * 32);
#pragma unroll
        for (int c = 0; c < 9; ++c) {
            bf16x8v bf = *(const bf16x8v*)(bB + c * (16 * 136) + kc * 32);
            acc[c] = __builtin_amdgcn_mfma_f32_16x16x32_bf16(af, bf, acc[c], 0, 0, 0);
        }
    }

    const int rowb = r0 + wv * 16 + quad * 4;
#pragma unroll
    for (int c = 0; c < 8; ++c) {
#pragma unroll
        for (int r = 0; r < 4; ++r) {
            int row = rowb + r;
            if (row < N) hout[(size_t)row * 128 + c * 16 + lc] = (short)f2bf_bits(acc[c][r]);
        }
    }
    // alpha columns: lc<8 -> as head lc; lc>=8 -> ad head lc-8
#pragma unroll
    for (int r = 0; r < 4; ++r) {
        int row = rowb + r;
        if (row < N) {
            if (lc < 8) as[row * 8 + lc] = acc[8][r];
            else        ad[row * 8 + (lc - 8)] = acc[8][r];
        }
    }
}

// ---------------------------------------------------------------------------
// Phase A: bucket edges by dst>>7 into per-block slabs. Register staging,
// packed uint32 = src | (dst&127)<<17. Hierarchical shfl scan.
// ---------------------------------------------------------------------------
__global__ __launch_bounds__(1024) void bucket_edges(const int* __restrict__ ei, int E,
                                                     unsigned* __restrict__ slab,
                                                     int* __restrict__ cntG,
                                                     int* __restrict__ startG) {
    __shared__ int hist[1024];
    __shared__ int cur[NBUCK];
    __shared__ int wpart[16];
    const int t = threadIdx.x;
    const int blk = blockIdx.x;
    const int base = blk * ABLK;
    int count = E - base; if (count > ABLK) count = ABLK;

    int sr[8], dr[8];
    hist[t] = 0;
#pragma unroll
    for (int k = 0; k < 8; ++k) {
        int i = k * 1024 + t;
        if (i < count) { sr[k] = ei[base + i]; dr[k] = ei[E + base + i]; }
    }
    __syncthreads();
#pragma unroll
    for (int k = 0; k < 8; ++k) {
        int i = k * 1024 + t;
        if (i < count) atomicAdd(&hist[dr[k] >> 7], 1);
    }
    __syncthreads();
    int v = hist[t];
    int lane = t & 63, wid = t >> 6;
    int sc = v;
#pragma unroll
    for (int off = 1; off < 64; off <<= 1) { int u = __shfl_up(sc, off); if (lane >= off) sc += u; }
    if (lane == 63) wpart[wid] = sc;
    __syncthreads();
    if (wid == 0 && lane < 16) {
        int wv = wpart[lane], wsum = wv;
#pragma unroll
        for (int off = 1; off < 16; off <<= 1) { int u = __shfl_up(wsum, off); if (lane >= off) wsum += u; }
        wpart[lane] = wsum - wv;
    }
    __syncthreads();
    int excl = sc - v + wpart[wid];
    if (t < NBUCK) {
        cntG[blk * NBUCK + t]   = v;
        startG[blk * NBUCK + t] = excl;
        cur[t] = excl;
    }
    __syncthreads();
#pragma unroll
    for (int k = 0; k < 8; ++k) {
        int i = k * 1024 + t;
        if (i < count) {
            int d = dr[k];
            int pos = atomicAdd(&cur[d >> 7], 1);
            slab[(size_t)blk * ABLK + pos] = (unsigned)sr[k] | ((unsigned)(d & 127) << 17);
        }
    }
}

// ---------------------------------------------------------------------------
// Phase B: per bucket of 128 dst nodes. Wave-per-segment LDS gather (no
// per-edge binary search), hist + scan -> rowS/rowE (fixed CAP region per
// bucket), place sortedSrc in the bucket's window.
// ---------------------------------------------------------------------------
__global__ __launch_bounds__(512) void build_csr(const unsigned* __restrict__ slab,
                                                 const int* __restrict__ cntG,
                                                 const int* __restrict__ startG,
                                                 int nblk, int N,
                                                 int* __restrict__ rowS,
                                                 int* __restrict__ rowE,
                                                 int* __restrict__ sortedSrc) {
    __shared__ int eL[CAP];
    __shared__ int incl[512];
    __shared__ int cS[512];
    __shared__ int stS[512];
    __shared__ int lp[128];
    __shared__ int wpart[8];
    __shared__ int halfSum;
    const int bb = blockIdx.x;
    const int t = threadIdx.x;
    const int nodeBase = bb << 7;
    const int bBase = bb * CAP;

    int c = 0, st = 0;
    if (t < nblk) { c = cntG[t * NBUCK + bb]; st = startG[t * NBUCK + bb]; }
    cS[t] = c; stS[t] = st;
    if (t < 128) lp[t] = 0;
    int lane = t & 63, wid = t >> 6;
    int sc = c;
#pragma unroll
    for (int off = 1; off < 64; off <<= 1) { int u = __shfl_up(sc, off); if (lane >= off) sc += u; }
    if (lane == 63) wpart[wid] = sc;
    __syncthreads();
    if (wid == 0 && lane < 8) {
        int wv = wpart[lane], wsum = wv;
#pragma unroll
        for (int off = 1; off < 8; off <<= 1) { int u = __shfl_up(wsum, off); if (lane >= off) wsum += u; }
        wpart[lane] = wsum - wv;
    }
    __syncthreads();
    incl[t] = sc + wpart[wid];
    __syncthreads();
    int total = incl[511];
    if (total > CAP) total = CAP;   // statically impossible; guards LDS OOB
    // wave-per-segment gather: wave handles segments wid, wid+8, ...
    for (int s = wid; s < nblk; s += 8) {
        int cc = cS[s];
        int off0 = incl[s] - cc;
        const unsigned* p = slab + (size_t)s * ABLK + stS[s];
        for (int i = lane; i < cc; i += 64) eL[off0 + i] = (int)p[i];
    }
    __syncthreads();
    for (int e = t; e < total; e += 512) atomicAdd(&lp[((unsigned)eL[e]) >> 17], 1);
    __syncthreads();
    // scan 128 node counts
    int cnt = 0, s2 = 0;
    if (t < 128) {
        cnt = lp[t];
        s2 = cnt;
#pragma unroll
        for (int off = 1; off < 64; off <<= 1) { int u = __shfl_up(s2, off); if (lane >= off) s2 += u; }
        if (t == 63) halfSum = s2;
    }
    __syncthreads();
    if (t < 128) {
        int inc2 = s2 + (t >= 64 ? halfSum : 0);
        int ex = inc2 - cnt;
        int gn = nodeBase + t;
        if (gn < N) { rowS[gn] = bBase + ex; rowE[gn] = bBase + ex + cnt; }
        lp[t] = ex;
    }
    __syncthreads();
    for (int e = t; e < total; e += 512) {
        unsigned pk = (unsigned)eL[e];
        int pos = atomicAdd(&lp[pk >> 17], 1);
        sortedSrc[bBase + pos] = (int)(pk & 0x1FFFFu);
    }
}

// ---------------------------------------------------------------------------
// Aggregate: one wave per dst node. Lane = (group g=lane>>3 strides edges by
// 8, p=lane&7 = head p, channels p*16..p*16+15 via 2 uint4 loads). 16 h-rows
// in flight per wave (cur+next x 8 groups). Butterfly xor 8/16/32; self-loop
// analytic post-butterfly; only group 0 stores.
// ---------------------------------------------------------------------------
__global__ __launch_bounds__(256) void aggregate(const int* __restrict__ rowS,
                                                 const int* __restrict__ rowE,
                                                 const int* __restrict__ sortedSrc,
                                                 const short* __restrict__ h,
                                                 const float* __restrict__ as,
                                                 const float* __restrict__ ad,
                                                 const float* __restrict__ bias,
                                                 float* __restrict__ out, int N) {
    int node = blockIdx.x * 4 + (threadIdx.x >> 6);
    if (node >= N) return;
    int lane = threadIdx.x & 63;
    int g = lane >> 3, p = lane & 7;
    int start = rowS[node], end = rowE[node];
    float adv = ad[node * 8 + p];

    float acc[16];
#pragma unroll
    for (int k = 0; k < 16; ++k) acc[k] = 0.f;
    float dsum = 0.f;

    int e = start + g;
    float asv = 0.f; uint4 h0, h1;
    if (e < end) {
        int j = sortedSrc[e];
        asv = as[j * 8 + p];
        const uint4* hp = (const uint4*)(h + (size_t)j * 128 + p * 16);
        h0 = hp[0]; h1 = hp[1];
    }
    while (e < end) {
        int en = e + 8;
        float asn = 0.f; uint4 n0, n1;
        if (en < end) {
            int jn = sortedSrc[en];
            asn = as[jn * 8 + p];
            const uint4* hp = (const uint4*)(h + (size_t)jn * 128 + p * 16);
            n0 = hp[0]; n1 = hp[1];
        }
        float tt = asv + adv;
        tt = tt > 0.f ? tt : NEG_SLOPE * tt;
        float w = __expf(tt);
        acc[0]  += w * bflo(h0.x); acc[1]  += w * bfhi(h0.x);
        acc[2]  += w * bflo(h0.y); acc[3]  += w * bfhi(h0.y);
        acc[4]  += w * bflo(h0.z); acc[5]  += w * bfhi(h0.z);
        acc[6]  += w * bflo(h0.w); acc[7]  += w * bfhi(h0.w);
        acc[8]  += w * bflo(h1.x); acc[9]  += w * bfhi(h1.x);
        acc[10] += w * bflo(h1.y); acc[11] += w * bfhi(h1.y);
        acc[12] += w * bflo(h1.z); acc[13] += w * bfhi(h1.z);
        acc[14] += w * bflo(h1.w); acc[15] += w * bfhi(h1.w);
        dsum += w;
        asv = asn; h0 = n0; h1 = n1; e = en;
    }
#pragma unroll
    for (int m = 8; m <= 32; m <<= 1) {
#pragma unroll
        for (int k = 0; k < 16; ++k) acc[k] += __shfl_xor(acc[k], m);
        dsum += __shfl_xor(dsum, m);
    }
    // self-loop (every lane adds it once, post-butterfly)
    {
        float tt = as[node * 8 + p] + adv;
        tt = tt > 0.f ? tt : NEG_SLOPE * tt;
        float w = __expf(tt);
        const uint4* hp = (const uint4*)(h + (size_t)node * 128 + p * 16);
        uint4 s0 = hp[0], s1 = hp[1];
        acc[0]  += w * bflo(s0.x); acc[1]  += w * bfhi(s0.x);
        acc[2]  += w * bflo(s0.y); acc[3]  += w * bfhi(s0.y);
        acc[4]  += w * bflo(s0.z); acc[5]  += w * bfhi(s0.z);
        acc[6]  += w * bflo(s0.w); acc[7]  += w * bfhi(s0.w);
        acc[8]  += w * bflo(s1.x); acc[9]  += w * bfhi(s1.x);
        acc[10] += w * bflo(s1.y); acc[11] += w * bfhi(s1.y);
        acc[12] += w * bflo(s1.z); acc[13] += w * bfhi(s1.z);
        acc[14] += w * bflo(s1.w); acc[15] += w * bfhi(s1.w);
        dsum += w;
    }
    if (g == 0) {
        float inv = 1.0f / (dsum + 1e-16f);
        float* op = out + (size_t)node * 128 + p * 16;
        const float* bp = bias + p * 16;
#pragma unroll
        for (int q = 0; q < 4; ++q) {
            float4 bv = *(const float4*)(bp + q * 4);
            float o0 = acc[q * 4 + 0] * inv + bv.x;
            float o1 = acc[q * 4 + 1] * inv + bv.y;
            float o2 = acc[q * 4 + 2] * inv + bv.z;
            float o3 = acc[q * 4 + 3] * inv + bv.w;
            o0 = o0 > 0.f ? o0 : 0.f; o1 = o1 > 0.f ? o1 : 0.f;
            o2 = o2 > 0.f ? o2 : 0.f; o3 = o3 > 0.f ? o3 : 0.f;
            *(float4*)(op + q * 4) = make_float4(o0, o1, o2, o3);
        }
    }
}

extern "C" void kernel_launch(void* const* d_in, const int* in_sizes, int n_in,
                              void* d_out, int out_size, void* d_ws, size_t ws_size,
                              hipStream_t stream) {
    const float* x     = (const float*)d_in[0];
    const int*   ei    = (const int*)d_in[1];
    const float* W     = (const float*)d_in[2];
    const float* a_src = (const float*)d_in[3];
    const float* a_dst = (const float*)d_in[4];
    const float* bias  = (const float*)d_in[5];
    float* out = (float*)d_out;

    const int N = in_sizes[0] / 128;   // 100000
    const int E = in_sizes[1] / 2;     // 1600000
    const int nblk = (E + ABLK - 1) / ABLK;  // 196

    char* ws = (char*)d_ws;
    size_t off = 0;
    auto alloc = [&](size_t bytes) { void* p = ws + off; off = (off + bytes + 255) & ~(size_t)255; return p; };
    short*    h         = (short*)alloc((size_t)N * 128 * 2);
    float*    as        = (float*)alloc((size_t)N * 8 * 4);
    float*    ad        = (float*)alloc((size_t)N * 8 * 4);
    unsigned* slab      = (unsigned*)alloc((size_t)nblk * ABLK * 4);
    int*      cntG      = (int*)alloc((size_t)nblk * NBUCK * 4);
    int*      startG    = (int*)alloc((size_t)nblk * NBUCK * 4);
    int*      sortedSrc = (int*)alloc((size_t)NBUCK * CAP * 4);
    int*      rowS      = (int*)alloc((size_t)N * 4);
    int*      rowE      = (int*)alloc((size_t)N * 4);
    short*    WtE       = (short*)alloc((size_t)144 * 128 * 2);

    prep_w<<<72, 256, 0, stream>>>(W, a_src, a_dst, WtE);
    gemm_mfma<<<(N + 63) / 64, 256, 0, stream>>>(x, WtE, h, as, ad, N);
    bucket_edges<<<nblk, 1024, 0, stream>>>(ei, E, slab, cntG, startG);
    build_csr<<<NBUCK, 512, 0, stream>>>(slab, cntG, startG, nblk, N, rowS, rowE, sortedSrc);
    aggregate<<<(N + 3) / 4, 256, 0, stream>>>(rowS, rowE, sortedSrc, h, as, ad, bias, out, N);
}